// Round 13
// baseline (9387.852 us; speedup 1.0000x reference)
//
#include <hip/hip_runtime.h>
#include <cmath>

#define TOK 4608      // B*N
#define DMODEL 768

typedef __attribute__((ext_vector_type(8))) _Float16 f16x8;
typedef __attribute__((ext_vector_type(4))) float f32x4;
typedef unsigned short ushort_t;

__device__ __forceinline__ float gelu_exact(float x) {
    return 0.5f * x * (1.0f + erff(x * 0.70710678118654752440f));
}

// 2-limb fp16 decomposition, RN both limbs. x = h + m/2048 + delta, |delta| <= 2^-22 |x|.
// m pre-scaled by 2048: never subnormal (robust to MFMA input-denorm flush).
// RN (unbiased) is essential: r3's truncated variant had biased error -> gate flips.
__device__ __forceinline__ void cvt2(float x, unsigned short& h, unsigned short& m)
{
    _Float16 hf = (_Float16)x;
    float r = (x - (float)hf) * 2048.0f;        // exact residual (Sterbenz), rescaled
    _Float16 mf = (_Float16)r;
    h = __builtin_bit_cast(unsigned short, hf);
    m = __builtin_bit_cast(unsigned short, mf);
}

__device__ __forceinline__ void cvt2_pack8(const float4 a, const float4 b,
                                           uint4& H, uint4& M)
{
    unsigned short h[8], m[8];
    cvt2(a.x, h[0], m[0]); cvt2(a.y, h[1], m[1]);
    cvt2(a.z, h[2], m[2]); cvt2(a.w, h[3], m[3]);
    cvt2(b.x, h[4], m[4]); cvt2(b.y, h[5], m[5]);
    cvt2(b.z, h[6], m[6]); cvt2(b.w, h[7], m[7]);
    H = (uint4){ (unsigned)h[0] | ((unsigned)h[1] << 16), (unsigned)h[2] | ((unsigned)h[3] << 16),
                 (unsigned)h[4] | ((unsigned)h[5] << 16), (unsigned)h[6] | ((unsigned)h[7] << 16) };
    M = (uint4){ (unsigned)m[0] | ((unsigned)m[1] << 16), (unsigned)m[2] | ((unsigned)m[3] << 16),
                 (unsigned)m[4] | ((unsigned)m[5] << 16), (unsigned)m[6] | ((unsigned)m[7] << 16) };
}

// ---------------- fp32 -> limb planes (all weights, once per launch) ----------------
// Same cvt2 as in-kernel staging -> the MFMA operand bits are IDENTICAL to r12.
__global__ __launch_bounds__(256)
void cvt_plane(const float* __restrict__ src, ushort_t* __restrict__ dh,
               ushort_t* __restrict__ dm, int n)
{
    int i = (blockIdx.x*256 + threadIdx.x) << 2;
    if (i >= n) return;
    float4 v = *(const float4*)(src + i);
    ushort4 H, M;
    cvt2(v.x, H.x, M.x); cvt2(v.y, H.y, M.y);
    cvt2(v.z, H.z, M.z); cvt2(v.w, H.w, M.w);
    *(ushort4*)(dh + i) = H;
    *(ushort4*)(dm + i) = M;
}

// ---------------- im2col: patches[tokid][k] (coalesced both sides) ----------------
__global__ __launch_bounds__(256)
void im2col_kernel(const float* __restrict__ x, float* __restrict__ patches)
{
    int idx = blockIdx.x*256 + threadIdx.x;   // tokid*256 + k
    int k = idx & 255, tokid = idx >> 8;
    int b = tokid / 576, n = tokid % 576;
    int hp = n / 24, wp = n % 24;
    patches[idx] = x[(size_t)b*147456 + (size_t)(hp*16 + (k >> 4))*384 + wp*16 + (k & 15)];
}

// ---------------- LayerNorm over D=768, one block per token (ln1) ----------------
__global__ __launch_bounds__(256)
void ln_kernel(const float* __restrict__ in, float* __restrict__ out,
               const float* __restrict__ g, const float* __restrict__ bta)
{
    int tokid = blockIdx.x;
    const float* xr = in + (size_t)tokid*768;
    int t = threadIdx.x;
    float v0 = xr[t], v1 = xr[t+256], v2 = xr[t+512];
    float s = v0+v1+v2, q = v0*v0+v1*v1+v2*v2;
    for (int off = 32; off > 0; off >>= 1) {
        s += __shfl_down(s, off);
        q += __shfl_down(q, off);
    }
    __shared__ float ss[4], sq[4];
    int wv = t >> 6, ln = t & 63;
    if (ln == 0) { ss[wv] = s; sq[wv] = q; }
    __syncthreads();
    float ts = ss[0]+ss[1]+ss[2]+ss[3];
    float tq = sq[0]+sq[1]+sq[2]+sq[3];
    float mean = ts * (1.f/768.f);
    float var  = tq * (1.f/768.f) - mean*mean;
    float inv  = rsqrtf(var + 1e-5f);
    float* orow = out + (size_t)tokid*768;
    orow[t]     = (v0-mean)*inv*g[t]     + bta[t];
    orow[t+256] = (v1-mean)*inv*g[t+256] + bta[t+256];
    orow[t+512] = (v2-mean)*inv*g[t+512] + bta[t+512];
}

// ---------------- fused ln2 + gate: LN output + scores/argmax/expert lists --------
// Gate FMA sequence identical (k = t, t+256, t+512) to the old standalone gate
// kernel -> bit-identical scores, zero flip risk.
__global__ __launch_bounds__(256)
void ln2_gate_kernel(const float* __restrict__ in, float* __restrict__ out,
                     const float* __restrict__ g, const float* __restrict__ bta,
                     const float* __restrict__ gw, const float* __restrict__ gb,
                     float* __restrict__ wgt, int* __restrict__ lists,
                     int* __restrict__ counts)
{
    int tokid = blockIdx.x;
    const float* xr = in + (size_t)tokid*768;
    int t = threadIdx.x;
    float v0 = xr[t], v1 = xr[t+256], v2 = xr[t+512];
    float s = v0+v1+v2, q = v0*v0+v1*v1+v2*v2;
    for (int off = 32; off > 0; off >>= 1) {
        s += __shfl_down(s, off);
        q += __shfl_down(q, off);
    }
    __shared__ float ss[4], sq[4];
    __shared__ float red[4][4];
    int wv = t >> 6, ln = t & 63;
    if (ln == 0) { ss[wv] = s; sq[wv] = q; }
    __syncthreads();
    float ts = ss[0]+ss[1]+ss[2]+ss[3];
    float tq = sq[0]+sq[1]+sq[2]+sq[3];
    float mean = ts * (1.f/768.f);
    float var  = tq * (1.f/768.f) - mean*mean;
    float inv  = rsqrtf(var + 1e-5f);
    float y0 = (v0-mean)*inv*g[t]     + bta[t];
    float y1 = (v1-mean)*inv*g[t+256] + bta[t+256];
    float y2 = (v2-mean)*inv*g[t+512] + bta[t+512];
    float* orow = out + (size_t)tokid*768;
    orow[t] = y0; orow[t+256] = y1; orow[t+512] = y2;

    float p0, p1, p2, p3;
    p0 = fmaf(y0, gw[t], 0.f);        p0 = fmaf(y1, gw[t+256], p0);        p0 = fmaf(y2, gw[t+512], p0);
    p1 = fmaf(y0, gw[768+t], 0.f);    p1 = fmaf(y1, gw[768+t+256], p1);    p1 = fmaf(y2, gw[768+t+512], p1);
    p2 = fmaf(y0, gw[1536+t], 0.f);   p2 = fmaf(y1, gw[1536+t+256], p2);   p2 = fmaf(y2, gw[1536+t+512], p2);
    p3 = fmaf(y0, gw[2304+t], 0.f);   p3 = fmaf(y1, gw[2304+t+256], p3);   p3 = fmaf(y2, gw[2304+t+512], p3);
    for (int off = 32; off > 0; off >>= 1) {
        p0 += __shfl_down(p0, off);
        p1 += __shfl_down(p1, off);
        p2 += __shfl_down(p2, off);
        p3 += __shfl_down(p3, off);
    }
    if (ln == 0) { red[wv][0]=p0; red[wv][1]=p1; red[wv][2]=p2; red[wv][3]=p3; }
    __syncthreads();
    if (t == 0) {
        float sc[4];
        #pragma unroll
        for (int e = 0; e < 4; ++e)
            sc[e] = red[0][e]+red[1][e]+red[2][e]+red[3][e] + gb[e];
        int best = 0; float bv = sc[0];
        #pragma unroll
        for (int e = 1; e < 4; ++e) if (sc[e] > bv) { bv = sc[e]; best = e; }  // first-max tie-break
        wgt[tokid] = bv;
        int pos = atomicAdd(&counts[best], 1);
        lists[best*TOK + pos] = tokid;
    }
}

// ---------------- MFMA NT GEMM (big): 128x128 tile, BK=32 ----------------
// A fp32 (cvt2 in staging); B = pre-converted limb planes (pure uint4 copies,
// no B-side conversion VALU in the K-loop). fp32 out.
// 3 MFMA terms (hh->acc1, hm+mh->acc2). launch_bounds(256,2): ~108 VGPR, no spill.
// SWZ: XCD-bijective block swizzle — dense grids only (r8 lesson: never on gather).
// mode 0: C=val  1: C+=val  2: C[gather]=gelu(val)  3: C[gather]+=wgt*val
// mode 4: C = val + pos[(row%576)*768+n]  (wgt doubles as pos pointer)
template<bool SWZ>
__global__ __launch_bounds__(256, 2)
void gemm_big(const float* __restrict__ A,
              const ushort_t* __restrict__ Bhp, const ushort_t* __restrict__ Bmp,
              const float* __restrict__ bias, float* __restrict__ C,
              int M, int Nout, int K, int ldA, int ldC, int mode,
              const int* __restrict__ lists, const int* __restrict__ counts,
              const float* __restrict__ wgt)
{
    int Meff = M;
    const int* gather = nullptr;
    if (counts) {
        int e = blockIdx.z;
        Meff   = counts[e];
        gather = lists + e * TOK;
        Bhp   += (size_t)e * Nout * K;
        Bmp   += (size_t)e * Nout * K;
        bias  += (size_t)e * Nout;
    }
    int m0, n0;
    if constexpr (SWZ) {
        int gx  = gridDim.x;
        int nwg = gx * gridDim.y;       // requires nwg % 8 == 0
        int bid = blockIdx.y * gx + blockIdx.x;
        bid = (bid & 7) * (nwg >> 3) + (bid >> 3);
        m0 = (bid / gx) << 7; n0 = (bid % gx) << 7;
    } else {
        m0 = blockIdx.y << 7; n0 = blockIdx.x << 7;
    }
    if (m0 >= Meff) return;

    __shared__ unsigned short Ah[128][40];
    __shared__ unsigned short Am[128][40];
    __shared__ unsigned short Bh[128][40];
    __shared__ unsigned short Bm[128][40];

    int t = threadIdx.x;
    int srow = t >> 1;               // staging row 0..127
    int koff = (t & 1) << 4;         // k-offset 0 or 16

    int ar = m0 + srow;
    long agrow = -1;
    if (ar < Meff) agrow = gather ? gather[ar] : ar;
    const float* Asrc = (agrow >= 0) ? (A + (size_t)agrow*ldA + koff) : nullptr;
    const ushort_t* Bh_src = Bhp + (size_t)(n0 + srow)*K + koff;
    const ushort_t* Bm_src = Bmp + (size_t)(n0 + srow)*K + koff;

    int lane = t & 63;
    int wv   = t >> 6;
    int wm   = (wv >> 1) << 6;
    int wn   = (wv & 1) << 6;
    int r16  = lane & 15;
    int g    = lane >> 4;

    f32x4 acc1[4][4], acc2[4][4];
    #pragma unroll
    for (int i = 0; i < 4; ++i)
        #pragma unroll
        for (int j = 0; j < 4; ++j) {
            acc1[i][j] = (f32x4){0.f, 0.f, 0.f, 0.f};
            acc2[i][j] = (f32x4){0.f, 0.f, 0.f, 0.f};
        }

    float4 ra[4];
    uint4  rbh[2], rbm[2];
    ra[0] = ra[1] = ra[2] = ra[3] = make_float4(0.f, 0.f, 0.f, 0.f);

    auto load_tile = [&](int k0) {
        if (Asrc) {
            ra[0] = *(const float4*)(Asrc + k0);
            ra[1] = *(const float4*)(Asrc + k0 + 4);
            ra[2] = *(const float4*)(Asrc + k0 + 8);
            ra[3] = *(const float4*)(Asrc + k0 + 12);
        }
        rbh[0] = *(const uint4*)(Bh_src + k0);
        rbh[1] = *(const uint4*)(Bh_src + k0 + 8);
        rbm[0] = *(const uint4*)(Bm_src + k0);
        rbm[1] = *(const uint4*)(Bm_src + k0 + 8);
    };

    load_tile(0);

    for (int k0 = 0; k0 < K; k0 += 32) {
        __syncthreads();
        {
            uint4 H, M_;
            cvt2_pack8(ra[0], ra[1], H, M_);
            *(uint4*)&Ah[srow][koff]   = H;
            *(uint4*)&Am[srow][koff]   = M_;
            cvt2_pack8(ra[2], ra[3], H, M_);
            *(uint4*)&Ah[srow][koff+8] = H;
            *(uint4*)&Am[srow][koff+8] = M_;
            *(uint4*)&Bh[srow][koff]   = rbh[0];
            *(uint4*)&Bh[srow][koff+8] = rbh[1];
            *(uint4*)&Bm[srow][koff]   = rbm[0];
            *(uint4*)&Bm[srow][koff+8] = rbm[1];
        }
        __syncthreads();
        if (k0 + 32 < K) load_tile(k0 + 32);   // prefetch hides under MFMA

        f16x8 fah[4], fam[4];
        #pragma unroll
        for (int i = 0; i < 4; ++i) {
            int ml = wm + i*16 + r16;
            fah[i] = *(const f16x8*)&Ah[ml][g*8];
            fam[i] = *(const f16x8*)&Am[ml][g*8];
        }
        #pragma unroll
        for (int j = 0; j < 4; ++j) {
            int nl = wn + j*16 + r16;
            f16x8 fbh = *(const f16x8*)&Bh[nl][g*8];
            f16x8 fbm = *(const f16x8*)&Bm[nl][g*8];
            #pragma unroll
            for (int i = 0; i < 4; ++i) {
                acc1[i][j] = __builtin_amdgcn_mfma_f32_16x16x32_f16(fah[i], fbh, acc1[i][j], 0, 0, 0);
                acc2[i][j] = __builtin_amdgcn_mfma_f32_16x16x32_f16(fah[i], fbm, acc2[i][j], 0, 0, 0);
                acc2[i][j] = __builtin_amdgcn_mfma_f32_16x16x32_f16(fam[i], fbh, acc2[i][j], 0, 0, 0);
            }
        }
    }

    const float MS = 1.0f / 2048.0f;
    float biasv[4];
    #pragma unroll
    for (int j = 0; j < 4; ++j) biasv[j] = bias[n0 + wn + j*16 + r16];

    #pragma unroll
    for (int i = 0; i < 4; ++i) {
        int mb = m0 + wm + i*16 + (g << 2);
        #pragma unroll
        for (int r = 0; r < 4; ++r) {
            int m = mb + r;
            if (m >= Meff) continue;
            int row = gather ? gather[m] : m;
            size_t rowoff = (size_t)row*ldC + n0 + wn + r16;
            float w = (mode == 3) ? wgt[row] : 0.f;
            #pragma unroll
            for (int j = 0; j < 4; ++j) {
                float val = acc1[i][j][r] + acc2[i][j][r] * MS + biasv[j];
                size_t off = rowoff + j*16;
                if      (mode == 0) C[off] = val;
                else if (mode == 1) C[off] += val;
                else if (mode == 2) C[off] = gelu_exact(val);
                else if (mode == 3) C[off] += w * val;
                else C[off] = val + wgt[(size_t)(row % 576)*768 + n0 + wn + j*16 + r16];
            }
        }
    }
}

// ---------------- MFMA NT GEMM (small): 64x64 tile, BK=64 ----------------
// For grids with fewer 128-tiles than CUs (out-proj, w2, patch).
// threads 0..127 stage A rows (fp32 + cvt); 128..255 stage B rows (plane copies).
// isA is wave-uniform (waves 0-1 vs 2-3) — no intra-wave divergence.
template<bool SWZ>
__global__ __launch_bounds__(256, 2)
void gemm_small(const float* __restrict__ A,
                const ushort_t* __restrict__ Bhp, const ushort_t* __restrict__ Bmp,
                const float* __restrict__ bias, float* __restrict__ C,
                int M, int Nout, int K, int ldA, int ldC, int mode,
                const int* __restrict__ lists, const int* __restrict__ counts,
                const float* __restrict__ wgt)
{
    int Meff = M;
    const int* gather = nullptr;
    if (counts) {
        int e = blockIdx.z;
        Meff   = counts[e];
        gather = lists + e * TOK;
        Bhp   += (size_t)e * Nout * K;
        Bmp   += (size_t)e * Nout * K;
        bias  += (size_t)e * Nout;
    }
    int m0, n0;
    if constexpr (SWZ) {
        int gx  = gridDim.x;
        int nwg = gx * gridDim.y;       // requires nwg % 8 == 0
        int bid = blockIdx.y * gx + blockIdx.x;
        bid = (bid & 7) * (nwg >> 3) + (bid >> 3);
        m0 = (bid / gx) << 6; n0 = (bid % gx) << 6;
    } else {
        m0 = blockIdx.y << 6; n0 = blockIdx.x << 6;
    }
    if (m0 >= Meff) return;

    __shared__ unsigned short Ah[64][72];
    __shared__ unsigned short Am[64][72];
    __shared__ unsigned short Bh[64][72];
    __shared__ unsigned short Bm[64][72];

    int t = threadIdx.x;
    int srow  = t >> 1;              // 0..127: <64 => A row, else B row
    int khalf = (t & 1) << 5;        // 0 or 32 (elements)
    bool isA = srow < 64;
    int row  = isA ? srow : (srow - 64);

    const float*    Afsrc  = nullptr;
    const ushort_t* Bh_src = nullptr;
    const ushort_t* Bm_src = nullptr;
    if (isA) {
        int ar = m0 + row;
        if (ar < Meff) {
            long agrow = gather ? gather[ar] : ar;
            Afsrc = A + (size_t)agrow*ldA + khalf;
        }
    } else {
        Bh_src = Bhp + (size_t)(n0 + row)*K + khalf;
        Bm_src = Bmp + (size_t)(n0 + row)*K + khalf;
    }

    int lane = t & 63;
    int wv   = t >> 6;
    int wm   = (wv >> 1) << 5;       // 0 / 32
    int wn   = (wv & 1) << 5;        // 0 / 32
    int r16  = lane & 15;
    int g    = lane >> 4;

    f32x4 acc1[2][2], acc2[2][2];
    #pragma unroll
    for (int i = 0; i < 2; ++i)
        #pragma unroll
        for (int j = 0; j < 2; ++j) {
            acc1[i][j] = (f32x4){0.f, 0.f, 0.f, 0.f};
            acc2[i][j] = (f32x4){0.f, 0.f, 0.f, 0.f};
        }

    uint4 rr[8];
    #pragma unroll
    for (int i = 0; i < 8; ++i) rr[i] = (uint4){0u, 0u, 0u, 0u};

    auto load_tile = [&](int k0) {
        if (isA) {
            if (Afsrc) {
                #pragma unroll
                for (int i = 0; i < 8; ++i)
                    rr[i] = *(const uint4*)(Afsrc + k0 + 4*i);   // 32 floats
            }
        } else {
            #pragma unroll
            for (int i = 0; i < 4; ++i) {
                rr[i]   = *(const uint4*)(Bh_src + k0 + 8*i);    // 32 h ushorts
                rr[4+i] = *(const uint4*)(Bm_src + k0 + 8*i);    // 32 m ushorts
            }
        }
    };

    auto stage = [&]() {
        if (isA) {
            #pragma unroll
            for (int i = 0; i < 8; i += 2) {
                uint4 H, M_;
                cvt2_pack8(*(const float4*)&rr[i], *(const float4*)&rr[i+1], H, M_);
                *(uint4*)&Ah[row][khalf + 4*i] = H;
                *(uint4*)&Am[row][khalf + 4*i] = M_;
            }
        } else {
            #pragma unroll
            for (int i = 0; i < 4; ++i) {
                *(uint4*)&Bh[row][khalf + 8*i] = rr[i];
                *(uint4*)&Bm[row][khalf + 8*i] = rr[4+i];
            }
        }
    };

    load_tile(0);

    for (int k0 = 0; k0 < K; k0 += 64) {
        __syncthreads();
        stage();
        __syncthreads();
        if (k0 + 64 < K) load_tile(k0 + 64);   // prefetch hides under MFMA

        #pragma unroll
        for (int ks = 0; ks < 2; ++ks) {
            f16x8 fah[2], fam[2];
            #pragma unroll
            for (int i = 0; i < 2; ++i) {
                int ml = wm + i*16 + r16;
                fah[i] = *(const f16x8*)&Ah[ml][ks*32 + g*8];
                fam[i] = *(const f16x8*)&Am[ml][ks*32 + g*8];
            }
            #pragma unroll
            for (int j = 0; j < 2; ++j) {
                int nl = wn + j*16 + r16;
                f16x8 fbh = *(const f16x8*)&Bh[nl][ks*32 + g*8];
                f16x8 fbm = *(const f16x8*)&Bm[nl][ks*32 + g*8];
                #pragma unroll
                for (int i = 0; i < 2; ++i) {
                    acc1[i][j] = __builtin_amdgcn_mfma_f32_16x16x32_f16(fah[i], fbh, acc1[i][j], 0, 0, 0);
                    acc2[i][j] = __builtin_amdgcn_mfma_f32_16x16x32_f16(fah[i], fbm, acc2[i][j], 0, 0, 0);
                    acc2[i][j] = __builtin_amdgcn_mfma_f32_16x16x32_f16(fam[i], fbh, acc2[i][j], 0, 0, 0);
                }
            }
        }
    }

    const float MS = 1.0f / 2048.0f;
    float biasv[2];
    #pragma unroll
    for (int j = 0; j < 2; ++j) biasv[j] = bias[n0 + wn + j*16 + r16];

    #pragma unroll
    for (int i = 0; i < 2; ++i) {
        int mb = m0 + wm + i*16 + (g << 2);
        #pragma unroll
        for (int r = 0; r < 4; ++r) {
            int m = mb + r;
            if (m >= Meff) continue;
            int rowc = gather ? gather[m] : m;
            size_t rowoff = (size_t)rowc*ldC + n0 + wn + r16;
            float w = (mode == 3) ? wgt[rowc] : 0.f;
            #pragma unroll
            for (int j = 0; j < 2; ++j) {
                float val = acc1[i][j][r] + acc2[i][j][r] * MS + biasv[j];
                size_t off = rowoff + j*16;
                if      (mode == 0) C[off] = val;
                else if (mode == 1) C[off] += val;
                else if (mode == 2) C[off] = gelu_exact(val);
                else if (mode == 3) C[off] += w * val;
                else C[off] = val + wgt[(size_t)(rowc % 576)*768 + n0 + wn + j*16 + r16];
            }
        }
    }
}

// ---------------- attention (MFMA flash): one block = 64 q-rows x (head, batch) ----
__global__ __launch_bounds__(256)
void attn_kernel(const float* __restrict__ qkv, float* __restrict__ attn)
{
    int q0 = blockIdx.x << 6;
    int h  = blockIdx.y;
    int b  = blockIdx.z;
    const float* base = qkv + (size_t)b * 576 * 2304;
    int qoff = h << 6, koff = 768 + (h << 6), voff = 1536 + (h << 6);

    __shared__ unsigned short Qh[64][72], Qm[64][72];
    __shared__ unsigned short Kh[64][72], Km[64][72];
    __shared__ unsigned short Vth[64][72], Vtm[64][72];   // transposed: [d][j]
    __shared__ unsigned short Ph[64][72], Pm[64][72];

    int t    = threadIdx.x;
    int lane = t & 63;
    int wq   = t >> 6;
    int l15  = lane & 15;
    int g    = lane >> 4;

    int srow = t >> 2;           // staging row 0..63
    int sq   = t & 3;            // quarter

    // ---- stage Q ----
    {
        const float* src = &base[(size_t)(q0 + srow)*2304 + qoff + (sq << 4)];
        #pragma unroll
        for (int k = 0; k < 16; k += 4) {
            float4 v = *(const float4*)(src + k);
            ushort4 hh, mm;
            cvt2(v.x, hh.x, mm.x); cvt2(v.y, hh.y, mm.y);
            cvt2(v.z, hh.z, mm.z); cvt2(v.w, hh.w, mm.w);
            *(ushort4*)&Qh[srow][(sq << 4) + k] = hh;
            *(ushort4*)&Qm[srow][(sq << 4) + k] = mm;
        }
    }
    __syncthreads();

    f16x8 fqh[2], fqm[2];
    #pragma unroll
    for (int ks = 0; ks < 2; ++ks) {
        fqh[ks] = *(const f16x8*)&Qh[wq*16 + l15][ks*32 + g*8];
        fqm[ks] = *(const f16x8*)&Qm[wq*16 + l15][ks*32 + g*8];
    }

    float4 rk[4], rv[4];
    {
        const float* ks_ = &base[(size_t)srow*2304 + koff + (sq << 4)];
        const float* vs_ = &base[(size_t)srow*2304 + voff + (sq << 2)];
        #pragma unroll
        for (int k = 0; k < 4; ++k) rk[k] = *(const float4*)(ks_ + 4*k);
        #pragma unroll
        for (int k = 0; k < 4; ++k) rv[k] = *(const float4*)(vs_ + 16*k);
    }

    f32x4 o1[4], o2[4];
    #pragma unroll
    for (int df = 0; df < 4; ++df) {
        o1[df] = (f32x4){0.f,0.f,0.f,0.f};
        o2[df] = (f32x4){0.f,0.f,0.f,0.f};
    }
    float m_[4] = {-3.4e38f,-3.4e38f,-3.4e38f,-3.4e38f};
    float l_[4] = {0.f,0.f,0.f,0.f};
    const float MS = 1.0f / 2048.0f;

    for (int j0 = 0; j0 < 576; j0 += 64) {
        __syncthreads();   // previous tile's LDS reads done
        #pragma unroll
        for (int k = 0; k < 4; ++k) {
            ushort4 hh, mm;
            cvt2(rk[k].x, hh.x, mm.x); cvt2(rk[k].y, hh.y, mm.y);
            cvt2(rk[k].z, hh.z, mm.z); cvt2(rk[k].w, hh.w, mm.w);
            *(ushort4*)&Kh[srow][(sq << 4) + 4*k] = hh;
            *(ushort4*)&Km[srow][(sq << 4) + 4*k] = mm;
        }
        #pragma unroll
        for (int k = 0; k < 4; ++k) {
            ushort4 hh, mm;
            cvt2(rv[k].x, hh.x, mm.x); cvt2(rv[k].y, hh.y, mm.y);
            cvt2(rv[k].z, hh.z, mm.z); cvt2(rv[k].w, hh.w, mm.w);
            int dbase = (sq << 2) + (k << 4);
            Vth[dbase+0][srow] = hh.x; Vtm[dbase+0][srow] = mm.x;
            Vth[dbase+1][srow] = hh.y; Vtm[dbase+1][srow] = mm.y;
            Vth[dbase+2][srow] = hh.z; Vtm[dbase+2][srow] = mm.z;
            Vth[dbase+3][srow] = hh.w; Vtm[dbase+3][srow] = mm.w;
        }
        __syncthreads();
        int jn = j0 + 64;
        if (jn < 576) {
            const float* ks_ = &base[(size_t)(jn + srow)*2304 + koff + (sq << 4)];
            const float* vs_ = &base[(size_t)(jn + srow)*2304 + voff + (sq << 2)];
            #pragma unroll
            for (int k = 0; k < 4; ++k) rk[k] = *(const float4*)(ks_ + 4*k);
            #pragma unroll
            for (int k = 0; k < 4; ++k) rv[k] = *(const float4*)(vs_ + 16*k);
        }

        // ---- QK^T ----
        f32x4 s1[4], s2[4];
        #pragma unroll
        for (int jf = 0; jf < 4; ++jf) {
            s1[jf] = (f32x4){0.f,0.f,0.f,0.f};
            s2[jf] = (f32x4){0.f,0.f,0.f,0.f};
        }
        #pragma unroll
        for (int jf = 0; jf < 4; ++jf) {
            #pragma unroll
            for (int ks = 0; ks < 2; ++ks) {
                f16x8 fkh = *(const f16x8*)&Kh[jf*16 + l15][ks*32 + g*8];
                f16x8 fkm = *(const f16x8*)&Km[jf*16 + l15][ks*32 + g*8];
                s1[jf] = __builtin_amdgcn_mfma_f32_16x16x32_f16(fqh[ks], fkh, s1[jf], 0, 0, 0);
                s2[jf] = __builtin_amdgcn_mfma_f32_16x16x32_f16(fqh[ks], fkm, s2[jf], 0, 0, 0);
                s2[jf] = __builtin_amdgcn_mfma_f32_16x16x32_f16(fqm[ks], fkh, s2[jf], 0, 0, 0);
            }
        }
        float p[4][4];
        #pragma unroll
        for (int jf = 0; jf < 4; ++jf)
            #pragma unroll
            for (int r = 0; r < 4; ++r)
                p[jf][r] = (s1[jf][r] + s2[jf][r]*MS) * 0.125f;

        // ---- online softmax ----
        #pragma unroll
        for (int r = 0; r < 4; ++r) {
            float tm = fmaxf(fmaxf(p[0][r], p[1][r]), fmaxf(p[2][r], p[3][r]));
            #pragma unroll
            for (int off = 8; off > 0; off >>= 1) tm = fmaxf(tm, __shfl_xor(tm, off, 16));
            float mn = fmaxf(m_[r], tm);
            float f  = expf(m_[r] - mn);
            m_[r] = mn;
            l_[r] *= f;
            #pragma unroll
            for (int df = 0; df < 4; ++df) { o1[df][r] *= f; o2[df][r] *= f; }
            float ps = 0.f;
            #pragma unroll
            for (int jf = 0; jf < 4; ++jf) {
                p[jf][r] = expf(p[jf][r] - mn);
                ps += p[jf][r];
            }
            #pragma unroll
            for (int off = 8; off > 0; off >>= 1) ps += __shfl_xor(ps, off, 16);
            l_[r] += ps;
        }
        #pragma unroll
        for (int jf = 0; jf < 4; ++jf)
            #pragma unroll
            for (int r = 0; r < 4; ++r) {
                unsigned short ph, pm;
                cvt2(p[jf][r], ph, pm);
                Ph[wq*16 + g*4 + r][jf*16 + l15] = ph;
                Pm[wq*16 + g*4 + r][jf*16 + l15] = pm;
            }

        // ---- PV ----
        #pragma unroll
        for (int ks = 0; ks < 2; ++ks) {
            f16x8 fph = *(const f16x8*)&Ph[wq*16 + l15][ks*32 + g*8];
            f16x8 fpm = *(const f16x8*)&Pm[wq*16 + l15][ks*32 + g*8];
            #pragma unroll
            for (int df = 0; df < 4; ++df) {
                f16x8 fvh = *(const f16x8*)&Vth[df*16 + l15][ks*32 + g*8];
                f16x8 fvm = *(const f16x8*)&Vtm[df*16 + l15][ks*32 + g*8];
                o1[df] = __builtin_amdgcn_mfma_f32_16x16x32_f16(fph, fvh, o1[df], 0, 0, 0);
                o2[df] = __builtin_amdgcn_mfma_f32_16x16x32_f16(fph, fvm, o2[df], 0, 0, 0);
                o2[df] = __builtin_amdgcn_mfma_f32_16x16x32_f16(fpm, fvh, o2[df], 0, 0, 0);
            }
        }
    }

    #pragma unroll
    for (int r = 0; r < 4; ++r) {
        float inv = 1.f / l_[r];
        size_t row = (size_t)(b*576 + q0 + wq*16 + g*4 + r)*768 + qoff + l15;
        #pragma unroll
        for (int df = 0; df < 4; ++df)
            attn[row + df*16] = (o1[df][r] + o2[df][r]*MS) * inv;
    }
}

// ---------------- zero all 12 layers' expert counts in one launch ----------------
__global__ void zero_counts48(int* counts) { if (threadIdx.x < 48) counts[threadIdx.x] = 0; }

// ---------------- final b (h w) c -> b c h w ----------------
__global__ __launch_bounds__(256)
void out_transpose(const float* __restrict__ tok, float* __restrict__ out)
{
    int idx = blockIdx.x*256 + threadIdx.x;   // ((b*768+d)*24+hp)*24+wp
    int wp = idx % 24;
    int hp = (idx / 24) % 24;
    int d  = (idx / 576) % 768;
    int b  = idx / (576*768);
    out[idx] = tok[(size_t)(b*576 + hp*24 + wp)*768 + d];
}

extern "C" void kernel_launch(void* const* d_in, const int* in_sizes, int n_in,
                              void* d_out, int out_size, void* d_ws, size_t ws_size,
                              hipStream_t stream)
{
    const float* x       = (const float*)d_in[0];
    const float* patch_w = (const float*)d_in[1];
    const float* patch_b = (const float*)d_in[2];
    const float* pos     = (const float*)d_in[3];
    const float* ln1_g   = (const float*)d_in[4];
    const float* ln1_b   = (const float*)d_in[5];
    const float* qkv_w   = (const float*)d_in[6];
    const float* qkv_b   = (const float*)d_in[7];
    const float* out_w   = (const float*)d_in[8];
    const float* out_b   = (const float*)d_in[9];
    const float* ln2_g   = (const float*)d_in[10];
    const float* ln2_b   = (const float*)d_in[11];
    const float* gate_w  = (const float*)d_in[12];
    const float* gate_b  = (const float*)d_in[13];
    const float* w1      = (const float*)d_in[14];
    const float* b1      = (const float*)d_in[15];
    const float* w2      = (const float*)d_in[16];
    const float* b2      = (const float*)d_in[17];
    float* out = (float*)d_out;

    // workspace layout (floats): tok | h | scratch{qkv,attn} (hid & patches alias scratch)
    //                            | wgt | lists | counts[48] | weight limb planes
    float* ws    = (float*)d_ws;
    float* tok   = ws;                       // 3,538,944
    float* h     = ws + 3538944;             // 3,538,944
    float* scr   = ws + 7077888;             // 14,155,776 (qkv 10,616,832 + attn 3,538,944)
    float* qkv   = scr;
    float* attn  = scr + 10616832;
    float* hid   = scr;                      // aliases qkv+attn (dead by FFN time)
    float* patches = scr;                    // 4608*256 (dead before layer loop)
    float* wgt   = ws + 21233664;            // 4608
    int*   lists = (int*)(ws + 21238272);    // 4*4608 (shared across layers)
    int*   counts= (int*)(ws + 21256704);    // 48 = 12 layers x 4 experts

    // weight limb planes: 255,000,576 elems per plane (510 MB each) -> 1.02 GB total
    ushort_t* wph = (ushort_t*)(ws + 21262336);
    ushort_t* wpm = wph + 255000576;
    const size_t OFF_PW  = 0;                 // 768*256
    const size_t OFF_QKV = 196608;            // 12 x 2304*768
    const size_t OFF_OUT = 21430272;          // 12 x 768*768
    const size_t OFF_W1  = 28508160;          // 12 x 4*3072*768
    const size_t OFF_W2  = 141754368;         // 12 x 4*768*3072

    // one-time (per launch) weight conversion — bit-identical cvt2 to in-kernel
    cvt_plane<<<   192, 256, 0, stream>>>(patch_w, wph + OFF_PW,  wpm + OFF_PW,  196608);
    cvt_plane<<< 20736, 256, 0, stream>>>(qkv_w,   wph + OFF_QKV, wpm + OFF_QKV, 21233664);
    cvt_plane<<<  6912, 256, 0, stream>>>(out_w,   wph + OFF_OUT, wpm + OFF_OUT, 7077888);
    cvt_plane<<<110592, 256, 0, stream>>>(w1,      wph + OFF_W1,  wpm + OFF_W1,  113246208);
    cvt_plane<<<110592, 256, 0, stream>>>(w2,      wph + OFF_W2,  wpm + OFF_W2,  113246208);

    zero_counts48<<<1, 64, 0, stream>>>(counts);

    // patch embed = im2col + small-tile MFMA GEMM (mode 4 adds pos embed); 864 blocks
    im2col_kernel<<<4608, 256, 0, stream>>>(x, patches);
    gemm_small<true><<<dim3(12,72,1), 256, 0, stream>>>(patches, wph + OFF_PW, wpm + OFF_PW,
                                                        patch_b, tok,
                                                        4608, 768, 256, 256, 768, 4,
                                                        nullptr, nullptr, pos);

    for (int l = 0; l < 12; ++l) {
        int* counts_l = counts + l*4;
        ln_kernel<<<4608, 256, 0, stream>>>(tok, h, ln1_g + l*768, ln1_b + l*768);
        gemm_big<true><<<dim3(18,36,1), 256, 0, stream>>>(h,
                                                          wph + OFF_QKV + (size_t)l*1769472,
                                                          wpm + OFF_QKV + (size_t)l*1769472,
                                                          qkv_b + l*2304, qkv,
                                                          4608, 2304, 768, 768, 2304, 0,
                                                          nullptr, nullptr, nullptr);
        attn_kernel<<<dim3(9,12,8), 256, 0, stream>>>(qkv, attn);
        gemm_small<true><<<dim3(12,72,1), 256, 0, stream>>>(attn,
                                                            wph + OFF_OUT + (size_t)l*589824,
                                                            wpm + OFF_OUT + (size_t)l*589824,
                                                            out_b + l*768, tok,
                                                            4608, 768, 768, 768, 768, 1,
                                                            nullptr, nullptr, nullptr);
        ln2_gate_kernel<<<4608, 256, 0, stream>>>(tok, h, ln2_g + l*768, ln2_b + l*768,
                                                  gate_w + l*3072, gate_b + l*4,
                                                  wgt, lists, counts_l);
        gemm_big<false><<<dim3(24,36,4), 256, 0, stream>>>(h,
                                                           wph + OFF_W1 + (size_t)l*9437184,
                                                           wpm + OFF_W1 + (size_t)l*9437184,
                                                           b1 + (size_t)l*4*3072, hid,
                                                           4608, 3072, 768, 768, 3072, 2,
                                                           lists, counts_l, nullptr);
        gemm_small<false><<<dim3(12,72,4), 256, 0, stream>>>(hid,
                                                             wph + OFF_W2 + (size_t)l*9437184,
                                                             wpm + OFF_W2 + (size_t)l*9437184,
                                                             b2 + (size_t)l*4*768, tok,
                                                             4608, 768, 3072, 3072, 768, 3,
                                                             lists, counts_l, wgt);
    }
    out_transpose<<<13824, 256, 0, stream>>>(tok, out);
}

// Round 14
// 8319.171 us; speedup vs baseline: 1.1285x; 1.1285x over previous
//
#include <hip/hip_runtime.h>
#include <cmath>

#define TOK 4608      // B*N
#define DMODEL 768

typedef __attribute__((ext_vector_type(8))) _Float16 f16x8;
typedef __attribute__((ext_vector_type(4))) float f32x4;

__device__ __forceinline__ float gelu_exact(float x) {
    return 0.5f * x * (1.0f + erff(x * 0.70710678118654752440f));
}

// 2-limb fp16 decomposition, RN both limbs. x = h + m/2048 + delta, |delta| <= 2^-22 |x|.
// m pre-scaled by 2048: never subnormal (robust to MFMA input-denorm flush).
// RN (unbiased) is essential: r3's truncated variant had biased error -> gate flips.
__device__ __forceinline__ void cvt2(float x, unsigned short& h, unsigned short& m)
{
    _Float16 hf = (_Float16)x;
    float r = (x - (float)hf) * 2048.0f;        // exact residual (Sterbenz), rescaled
    _Float16 mf = (_Float16)r;
    h = __builtin_bit_cast(unsigned short, hf);
    m = __builtin_bit_cast(unsigned short, mf);
}

__device__ __forceinline__ void cvt2_pack8(const float4 a, const float4 b,
                                           uint4& H, uint4& M)
{
    unsigned short h[8], m[8];
    cvt2(a.x, h[0], m[0]); cvt2(a.y, h[1], m[1]);
    cvt2(a.z, h[2], m[2]); cvt2(a.w, h[3], m[3]);
    cvt2(b.x, h[4], m[4]); cvt2(b.y, h[5], m[5]);
    cvt2(b.z, h[6], m[6]); cvt2(b.w, h[7], m[7]);
    H = (uint4){ (unsigned)h[0] | ((unsigned)h[1] << 16), (unsigned)h[2] | ((unsigned)h[3] << 16),
                 (unsigned)h[4] | ((unsigned)h[5] << 16), (unsigned)h[6] | ((unsigned)h[7] << 16) };
    M = (uint4){ (unsigned)m[0] | ((unsigned)m[1] << 16), (unsigned)m[2] | ((unsigned)m[3] << 16),
                 (unsigned)m[4] | ((unsigned)m[5] << 16), (unsigned)m[6] | ((unsigned)m[7] << 16) };
}

// ---------------- im2col: patches[tokid][k] (coalesced both sides) ----------------
__global__ __launch_bounds__(256)
void im2col_kernel(const float* __restrict__ x, float* __restrict__ patches)
{
    int idx = blockIdx.x*256 + threadIdx.x;   // tokid*256 + k
    int k = idx & 255, tokid = idx >> 8;
    int b = tokid / 576, n = tokid % 576;
    int hp = n / 24, wp = n % 24;
    patches[idx] = x[(size_t)b*147456 + (size_t)(hp*16 + (k >> 4))*384 + wp*16 + (k & 15)];
}

// ---------------- LayerNorm over D=768, one block per token (ln1) ----------------
__global__ __launch_bounds__(256)
void ln_kernel(const float* __restrict__ in, float* __restrict__ out,
               const float* __restrict__ g, const float* __restrict__ bta)
{
    int tokid = blockIdx.x;
    const float* xr = in + (size_t)tokid*768;
    int t = threadIdx.x;
    float v0 = xr[t], v1 = xr[t+256], v2 = xr[t+512];
    float s = v0+v1+v2, q = v0*v0+v1*v1+v2*v2;
    for (int off = 32; off > 0; off >>= 1) {
        s += __shfl_down(s, off);
        q += __shfl_down(q, off);
    }
    __shared__ float ss[4], sq[4];
    int wv = t >> 6, ln = t & 63;
    if (ln == 0) { ss[wv] = s; sq[wv] = q; }
    __syncthreads();
    float ts = ss[0]+ss[1]+ss[2]+ss[3];
    float tq = sq[0]+sq[1]+sq[2]+sq[3];
    float mean = ts * (1.f/768.f);
    float var  = tq * (1.f/768.f) - mean*mean;
    float inv  = rsqrtf(var + 1e-5f);
    float* orow = out + (size_t)tokid*768;
    orow[t]     = (v0-mean)*inv*g[t]     + bta[t];
    orow[t+256] = (v1-mean)*inv*g[t+256] + bta[t+256];
    orow[t+512] = (v2-mean)*inv*g[t+512] + bta[t+512];
}

// ---------------- fused ln2 + gate: LN output + scores/argmax/expert lists --------
// Gate FMA sequence identical (k = t, t+256, t+512) to the old standalone gate
// kernel -> bit-identical scores, zero flip risk.
__global__ __launch_bounds__(256)
void ln2_gate_kernel(const float* __restrict__ in, float* __restrict__ out,
                     const float* __restrict__ g, const float* __restrict__ bta,
                     const float* __restrict__ gw, const float* __restrict__ gb,
                     float* __restrict__ wgt, int* __restrict__ lists,
                     int* __restrict__ counts)
{
    int tokid = blockIdx.x;
    const float* xr = in + (size_t)tokid*768;
    int t = threadIdx.x;
    float v0 = xr[t], v1 = xr[t+256], v2 = xr[t+512];
    float s = v0+v1+v2, q = v0*v0+v1*v1+v2*v2;
    for (int off = 32; off > 0; off >>= 1) {
        s += __shfl_down(s, off);
        q += __shfl_down(q, off);
    }
    __shared__ float ss[4], sq[4];
    __shared__ float red[4][4];
    int wv = t >> 6, ln = t & 63;
    if (ln == 0) { ss[wv] = s; sq[wv] = q; }
    __syncthreads();
    float ts = ss[0]+ss[1]+ss[2]+ss[3];
    float tq = sq[0]+sq[1]+sq[2]+sq[3];
    float mean = ts * (1.f/768.f);
    float var  = tq * (1.f/768.f) - mean*mean;
    float inv  = rsqrtf(var + 1e-5f);
    float y0 = (v0-mean)*inv*g[t]     + bta[t];
    float y1 = (v1-mean)*inv*g[t+256] + bta[t+256];
    float y2 = (v2-mean)*inv*g[t+512] + bta[t+512];
    float* orow = out + (size_t)tokid*768;
    orow[t] = y0; orow[t+256] = y1; orow[t+512] = y2;

    float p0, p1, p2, p3;
    p0 = fmaf(y0, gw[t], 0.f);        p0 = fmaf(y1, gw[t+256], p0);        p0 = fmaf(y2, gw[t+512], p0);
    p1 = fmaf(y0, gw[768+t], 0.f);    p1 = fmaf(y1, gw[768+t+256], p1);    p1 = fmaf(y2, gw[768+t+512], p1);
    p2 = fmaf(y0, gw[1536+t], 0.f);   p2 = fmaf(y1, gw[1536+t+256], p2);   p2 = fmaf(y2, gw[1536+t+512], p2);
    p3 = fmaf(y0, gw[2304+t], 0.f);   p3 = fmaf(y1, gw[2304+t+256], p3);   p3 = fmaf(y2, gw[2304+t+512], p3);
    for (int off = 32; off > 0; off >>= 1) {
        p0 += __shfl_down(p0, off);
        p1 += __shfl_down(p1, off);
        p2 += __shfl_down(p2, off);
        p3 += __shfl_down(p3, off);
    }
    if (ln == 0) { red[wv][0]=p0; red[wv][1]=p1; red[wv][2]=p2; red[wv][3]=p3; }
    __syncthreads();
    if (t == 0) {
        float sc[4];
        #pragma unroll
        for (int e = 0; e < 4; ++e)
            sc[e] = red[0][e]+red[1][e]+red[2][e]+red[3][e] + gb[e];
        int best = 0; float bv = sc[0];
        #pragma unroll
        for (int e = 1; e < 4; ++e) if (sc[e] > bv) { bv = sc[e]; best = e; }  // first-max tie-break
        wgt[tokid] = bv;
        int pos = atomicAdd(&counts[best], 1);
        lists[best*TOK + pos] = tokid;
    }
}

// ---------------- MFMA NT GEMM (wide): 256x128 tile, BK=32, 512 thr / 8 waves ----
// BM=256 halves B-panel re-reads vs 128-tiles (GEMMs are fetch-traffic bound:
// r12 traffic model 2.9 GB/layer ~= measured GEMM time at HBM BW).
// Per-wave work & MFMA order identical to r12's gemm_big -> bit-identical outputs.
// fp32 A/B in, cvt2 in staging; fp32 out. 3 MFMA terms (hh->acc1, hm+mh->acc2).
// launch_bounds(512,2): VGPR cap 256, est ~200 -> no spill (r9 tripwire: WRITE_SIZE).
// LDS (256+128)x40x2x2B = 60KB -> 2 blocks/CU = 16 waves/CU.
// SWZ: m204 bijective XCD swizzle (works for any nwg) — dense grids only (r8).
// mode 0: C=val  1: C+=val  2: C[gather]=gelu(val)  3: C[gather]+=wgt*val
template<bool SWZ>
__global__ __launch_bounds__(512, 2)
void gemm_wide(const float* __restrict__ A, const float* __restrict__ Bw,
               const float* __restrict__ bias, float* __restrict__ C,
               int M, int Nout, int K, int ldA, int ldC, int mode,
               const int* __restrict__ lists, const int* __restrict__ counts,
               const float* __restrict__ wgt)
{
    int Meff = M;
    const int* gather = nullptr;
    if (counts) {
        int e = blockIdx.z;
        Meff   = counts[e];
        gather = lists + e * TOK;
        Bw    += (size_t)e * Nout * K;
        bias  += (size_t)e * Nout;
    }
    int gx  = gridDim.x;
    int bid = blockIdx.y * gx + blockIdx.x;
    if constexpr (SWZ) {
        int nwg = gx * gridDim.y;
        int qq = nwg >> 3, rr8 = nwg & 7;
        int xcd = bid & 7, idx = bid >> 3;
        bid = (xcd < rr8 ? xcd*(qq+1) : rr8*(qq+1) + (xcd-rr8)*qq) + idx;  // bijective (m204)
    }
    int m0 = (bid / gx) << 8;        // 256-row tiles
    int n0 = (bid % gx) << 7;        // 128-col tiles
    if (m0 >= Meff) return;

    __shared__ unsigned short Ah[256][40];
    __shared__ unsigned short Am[256][40];
    __shared__ unsigned short Bh[128][40];
    __shared__ unsigned short Bm[128][40];

    int t = threadIdx.x;
    int srow  = t >> 1;              // A staging row 0..255
    int koff  = (t & 1) << 4;        // A k-offset 0 or 16
    int brow  = t >> 2;              // B staging row 0..127
    int bkoff = (t & 3) << 3;        // B k-offset 0,8,16,24

    int ar = m0 + srow;
    long agrow = -1;
    if (ar < Meff) agrow = gather ? gather[ar] : ar;
    const float* Asrc = (agrow >= 0) ? (A + (size_t)agrow*ldA + koff) : nullptr;
    const float* Bsrc = Bw + (size_t)(n0 + brow)*K + bkoff;

    int lane = t & 63;
    int wv   = t >> 6;               // 0..7
    int wm   = (wv >> 1) << 6;       // 0,64,128,192
    int wn   = (wv & 1) << 6;        // 0,64
    int r16  = lane & 15;
    int g    = lane >> 4;

    f32x4 acc1[4][4], acc2[4][4];
    #pragma unroll
    for (int i = 0; i < 4; ++i)
        #pragma unroll
        for (int j = 0; j < 4; ++j) {
            acc1[i][j] = (f32x4){0.f, 0.f, 0.f, 0.f};
            acc2[i][j] = (f32x4){0.f, 0.f, 0.f, 0.f};
        }

    float4 ra[4], rb0, rb1;
    ra[0] = ra[1] = ra[2] = ra[3] = make_float4(0.f, 0.f, 0.f, 0.f);

    auto load_tile = [&](int k0) {
        if (Asrc) {
            ra[0] = *(const float4*)(Asrc + k0);
            ra[1] = *(const float4*)(Asrc + k0 + 4);
            ra[2] = *(const float4*)(Asrc + k0 + 8);
            ra[3] = *(const float4*)(Asrc + k0 + 12);
        }
        rb0 = *(const float4*)(Bsrc + k0);
        rb1 = *(const float4*)(Bsrc + k0 + 4);
    };

    load_tile(0);

    for (int k0 = 0; k0 < K; k0 += 32) {
        __syncthreads();
        {
            uint4 H, M_;
            cvt2_pack8(ra[0], ra[1], H, M_);
            *(uint4*)&Ah[srow][koff]   = H;
            *(uint4*)&Am[srow][koff]   = M_;
            cvt2_pack8(ra[2], ra[3], H, M_);
            *(uint4*)&Ah[srow][koff+8] = H;
            *(uint4*)&Am[srow][koff+8] = M_;
            cvt2_pack8(rb0, rb1, H, M_);
            *(uint4*)&Bh[brow][bkoff]  = H;
            *(uint4*)&Bm[brow][bkoff]  = M_;
        }
        __syncthreads();
        if (k0 + 32 < K) load_tile(k0 + 32);   // prefetch hides under MFMA

        f16x8 fah[4], fam[4];
        #pragma unroll
        for (int i = 0; i < 4; ++i) {
            int ml = wm + i*16 + r16;
            fah[i] = *(const f16x8*)&Ah[ml][g*8];
            fam[i] = *(const f16x8*)&Am[ml][g*8];
        }
        #pragma unroll
        for (int j = 0; j < 4; ++j) {
            int nl = wn + j*16 + r16;
            f16x8 fbh = *(const f16x8*)&Bh[nl][g*8];
            f16x8 fbm = *(const f16x8*)&Bm[nl][g*8];
            #pragma unroll
            for (int i = 0; i < 4; ++i) {
                acc1[i][j] = __builtin_amdgcn_mfma_f32_16x16x32_f16(fah[i], fbh, acc1[i][j], 0, 0, 0);
                acc2[i][j] = __builtin_amdgcn_mfma_f32_16x16x32_f16(fah[i], fbm, acc2[i][j], 0, 0, 0);
                acc2[i][j] = __builtin_amdgcn_mfma_f32_16x16x32_f16(fam[i], fbh, acc2[i][j], 0, 0, 0);
            }
        }
    }

    const float MS = 1.0f / 2048.0f;
    float biasv[4];
    #pragma unroll
    for (int j = 0; j < 4; ++j) biasv[j] = bias[n0 + wn + j*16 + r16];

    #pragma unroll
    for (int i = 0; i < 4; ++i) {
        int mb = m0 + wm + i*16 + (g << 2);
        #pragma unroll
        for (int r = 0; r < 4; ++r) {
            int m = mb + r;
            if (m >= Meff) continue;
            int row = gather ? gather[m] : m;
            size_t rowoff = (size_t)row*ldC + n0 + wn + r16;
            float w = (mode == 3) ? wgt[row] : 0.f;
            #pragma unroll
            for (int j = 0; j < 4; ++j) {
                float val = acc1[i][j][r] + acc2[i][j][r] * MS + biasv[j];
                size_t off = rowoff + j*16;
                if      (mode == 0) C[off] = val;
                else if (mode == 1) C[off] += val;
                else if (mode == 2) C[off] = gelu_exact(val);
                else                C[off] += w * val;
            }
        }
    }
}

// ---------------- MFMA NT GEMM (small): 64x64 tile, BK=64 — patch embed only ------
// threads 0..127 stage A rows, 128..255 stage B rows (32 floats each).
// mode 4: C = val + pos[(row%576)*768+n]  (wgt doubles as pos pointer)
template<bool SWZ>
__global__ __launch_bounds__(256, 2)
void gemm_small(const float* __restrict__ A, const float* __restrict__ Bw,
                const float* __restrict__ bias, float* __restrict__ C,
                int M, int Nout, int K, int ldA, int ldC, int mode,
                const int* __restrict__ lists, const int* __restrict__ counts,
                const float* __restrict__ wgt)
{
    int Meff = M;
    const int* gather = nullptr;
    if (counts) {
        int e = blockIdx.z;
        Meff   = counts[e];
        gather = lists + e * TOK;
        Bw    += (size_t)e * Nout * K;
        bias  += (size_t)e * Nout;
    }
    int m0, n0;
    if constexpr (SWZ) {
        int gx  = gridDim.x;
        int nwg = gx * gridDim.y;       // requires nwg % 8 == 0 at call sites
        int bid = blockIdx.y * gx + blockIdx.x;
        bid = (bid & 7) * (nwg >> 3) + (bid >> 3);
        m0 = (bid / gx) << 6; n0 = (bid % gx) << 6;
    } else {
        m0 = blockIdx.y << 6; n0 = blockIdx.x << 6;
    }
    if (m0 >= Meff) return;

    __shared__ unsigned short Ah[64][72];
    __shared__ unsigned short Am[64][72];
    __shared__ unsigned short Bh[64][72];
    __shared__ unsigned short Bm[64][72];

    int t = threadIdx.x;
    int srow  = t >> 1;              // 0..127: <64 => A row, else B row
    int khalf = (t & 1) << 5;        // 0 or 32
    bool isA = srow < 64;
    int row  = isA ? srow : (srow - 64);

    const float* src = nullptr;
    if (isA) {
        int ar = m0 + row;
        if (ar < Meff) {
            long agrow = gather ? gather[ar] : ar;
            src = A + (size_t)agrow*ldA + khalf;
        }
    } else {
        src = Bw + (size_t)(n0 + row)*K + khalf;
    }

    int lane = t & 63;
    int wv   = t >> 6;
    int wm   = (wv >> 1) << 5;       // 0 / 32
    int wn   = (wv & 1) << 5;        // 0 / 32
    int r16  = lane & 15;
    int g    = lane >> 4;

    f32x4 acc1[2][2], acc2[2][2];
    #pragma unroll
    for (int i = 0; i < 2; ++i)
        #pragma unroll
        for (int j = 0; j < 2; ++j) {
            acc1[i][j] = (f32x4){0.f, 0.f, 0.f, 0.f};
            acc2[i][j] = (f32x4){0.f, 0.f, 0.f, 0.f};
        }

    float4 rr[8];
    #pragma unroll
    for (int i = 0; i < 8; ++i) rr[i] = make_float4(0.f, 0.f, 0.f, 0.f);

    auto load_tile = [&](int k0) {
        if (src) {
            #pragma unroll
            for (int i = 0; i < 8; ++i) rr[i] = *(const float4*)(src + k0 + 4*i);
        }
    };

    load_tile(0);

    for (int k0 = 0; k0 < K; k0 += 64) {
        __syncthreads();
        {
            unsigned short (*Xh)[72] = isA ? Ah : Bh;
            unsigned short (*Xm)[72] = isA ? Am : Bm;
            #pragma unroll
            for (int i = 0; i < 8; i += 2) {
                uint4 H, M_;
                cvt2_pack8(rr[i], rr[i+1], H, M_);
                *(uint4*)&Xh[row][khalf + 4*i] = H;
                *(uint4*)&Xm[row][khalf + 4*i] = M_;
            }
        }
        __syncthreads();
        if (k0 + 64 < K) load_tile(k0 + 64);   // prefetch hides under MFMA

        #pragma unroll
        for (int ks = 0; ks < 2; ++ks) {
            f16x8 fah[2], fam[2];
            #pragma unroll
            for (int i = 0; i < 2; ++i) {
                int ml = wm + i*16 + r16;
                fah[i] = *(const f16x8*)&Ah[ml][ks*32 + g*8];
                fam[i] = *(const f16x8*)&Am[ml][ks*32 + g*8];
            }
            #pragma unroll
            for (int j = 0; j < 2; ++j) {
                int nl = wn + j*16 + r16;
                f16x8 fbh = *(const f16x8*)&Bh[nl][ks*32 + g*8];
                f16x8 fbm = *(const f16x8*)&Bm[nl][ks*32 + g*8];
                #pragma unroll
                for (int i = 0; i < 2; ++i) {
                    acc1[i][j] = __builtin_amdgcn_mfma_f32_16x16x32_f16(fah[i], fbh, acc1[i][j], 0, 0, 0);
                    acc2[i][j] = __builtin_amdgcn_mfma_f32_16x16x32_f16(fah[i], fbm, acc2[i][j], 0, 0, 0);
                    acc2[i][j] = __builtin_amdgcn_mfma_f32_16x16x32_f16(fam[i], fbh, acc2[i][j], 0, 0, 0);
                }
            }
        }
    }

    const float MS = 1.0f / 2048.0f;
    float biasv[2];
    #pragma unroll
    for (int j = 0; j < 2; ++j) biasv[j] = bias[n0 + wn + j*16 + r16];

    #pragma unroll
    for (int i = 0; i < 2; ++i) {
        int mb = m0 + wm + i*16 + (g << 2);
        #pragma unroll
        for (int r = 0; r < 4; ++r) {
            int m = mb + r;
            if (m >= Meff) continue;
            int rowc = gather ? gather[m] : m;
            size_t rowoff = (size_t)rowc*ldC + n0 + wn + r16;
            float w = (mode == 3) ? wgt[rowc] : 0.f;
            #pragma unroll
            for (int j = 0; j < 2; ++j) {
                float val = acc1[i][j][r] + acc2[i][j][r] * MS + biasv[j];
                size_t off = rowoff + j*16;
                if      (mode == 0) C[off] = val;
                else if (mode == 1) C[off] += val;
                else if (mode == 2) C[off] = gelu_exact(val);
                else if (mode == 3) C[off] += w * val;
                else C[off] = val + wgt[(size_t)(rowc % 576)*768 + n0 + wn + j*16 + r16];
            }
        }
    }
}

// ---------------- attention (MFMA flash): one block = 64 q-rows x (head, batch) ----
__global__ __launch_bounds__(256)
void attn_kernel(const float* __restrict__ qkv, float* __restrict__ attn)
{
    int q0 = blockIdx.x << 6;
    int h  = blockIdx.y;
    int b  = blockIdx.z;
    const float* base = qkv + (size_t)b * 576 * 2304;
    int qoff = h << 6, koff = 768 + (h << 6), voff = 1536 + (h << 6);

    __shared__ unsigned short Qh[64][72], Qm[64][72];
    __shared__ unsigned short Kh[64][72], Km[64][72];
    __shared__ unsigned short Vth[64][72], Vtm[64][72];   // transposed: [d][j]
    __shared__ unsigned short Ph[64][72], Pm[64][72];

    int t    = threadIdx.x;
    int lane = t & 63;
    int wq   = t >> 6;
    int l15  = lane & 15;
    int g    = lane >> 4;

    int srow = t >> 2;           // staging row 0..63
    int sq   = t & 3;            // quarter

    // ---- stage Q ----
    {
        const float* src = &base[(size_t)(q0 + srow)*2304 + qoff + (sq << 4)];
        #pragma unroll
        for (int k = 0; k < 16; k += 4) {
            float4 v = *(const float4*)(src + k);
            ushort4 hh, mm;
            cvt2(v.x, hh.x, mm.x); cvt2(v.y, hh.y, mm.y);
            cvt2(v.z, hh.z, mm.z); cvt2(v.w, hh.w, mm.w);
            *(ushort4*)&Qh[srow][(sq << 4) + k] = hh;
            *(ushort4*)&Qm[srow][(sq << 4) + k] = mm;
        }
    }
    __syncthreads();

    f16x8 fqh[2], fqm[2];
    #pragma unroll
    for (int ks = 0; ks < 2; ++ks) {
        fqh[ks] = *(const f16x8*)&Qh[wq*16 + l15][ks*32 + g*8];
        fqm[ks] = *(const f16x8*)&Qm[wq*16 + l15][ks*32 + g*8];
    }

    float4 rk[4], rv[4];
    {
        const float* ks_ = &base[(size_t)srow*2304 + koff + (sq << 4)];
        const float* vs_ = &base[(size_t)srow*2304 + voff + (sq << 2)];
        #pragma unroll
        for (int k = 0; k < 4; ++k) rk[k] = *(const float4*)(ks_ + 4*k);
        #pragma unroll
        for (int k = 0; k < 4; ++k) rv[k] = *(const float4*)(vs_ + 16*k);
    }

    f32x4 o1[4], o2[4];
    #pragma unroll
    for (int df = 0; df < 4; ++df) {
        o1[df] = (f32x4){0.f,0.f,0.f,0.f};
        o2[df] = (f32x4){0.f,0.f,0.f,0.f};
    }
    float m_[4] = {-3.4e38f,-3.4e38f,-3.4e38f,-3.4e38f};
    float l_[4] = {0.f,0.f,0.f,0.f};
    const float MS = 1.0f / 2048.0f;

    for (int j0 = 0; j0 < 576; j0 += 64) {
        __syncthreads();   // previous tile's LDS reads done
        #pragma unroll
        for (int k = 0; k < 4; ++k) {
            ushort4 hh, mm;
            cvt2(rk[k].x, hh.x, mm.x); cvt2(rk[k].y, hh.y, mm.y);
            cvt2(rk[k].z, hh.z, mm.z); cvt2(rk[k].w, hh.w, mm.w);
            *(ushort4*)&Kh[srow][(sq << 4) + 4*k] = hh;
            *(ushort4*)&Km[srow][(sq << 4) + 4*k] = mm;
        }
        #pragma unroll
        for (int k = 0; k < 4; ++k) {
            ushort4 hh, mm;
            cvt2(rv[k].x, hh.x, mm.x); cvt2(rv[k].y, hh.y, mm.y);
            cvt2(rv[k].z, hh.z, mm.z); cvt2(rv[k].w, hh.w, mm.w);
            int dbase = (sq << 2) + (k << 4);
            Vth[dbase+0][srow] = hh.x; Vtm[dbase+0][srow] = mm.x;
            Vth[dbase+1][srow] = hh.y; Vtm[dbase+1][srow] = mm.y;
            Vth[dbase+2][srow] = hh.z; Vtm[dbase+2][srow] = mm.z;
            Vth[dbase+3][srow] = hh.w; Vtm[dbase+3][srow] = mm.w;
        }
        __syncthreads();
        int jn = j0 + 64;
        if (jn < 576) {
            const float* ks_ = &base[(size_t)(jn + srow)*2304 + koff + (sq << 4)];
            const float* vs_ = &base[(size_t)(jn + srow)*2304 + voff + (sq << 2)];
            #pragma unroll
            for (int k = 0; k < 4; ++k) rk[k] = *(const float4*)(ks_ + 4*k);
            #pragma unroll
            for (int k = 0; k < 4; ++k) rv[k] = *(const float4*)(vs_ + 16*k);
        }

        // ---- QK^T ----
        f32x4 s1[4], s2[4];
        #pragma unroll
        for (int jf = 0; jf < 4; ++jf) {
            s1[jf] = (f32x4){0.f,0.f,0.f,0.f};
            s2[jf] = (f32x4){0.f,0.f,0.f,0.f};
        }
        #pragma unroll
        for (int jf = 0; jf < 4; ++jf) {
            #pragma unroll
            for (int ks = 0; ks < 2; ++ks) {
                f16x8 fkh = *(const f16x8*)&Kh[jf*16 + l15][ks*32 + g*8];
                f16x8 fkm = *(const f16x8*)&Km[jf*16 + l15][ks*32 + g*8];
                s1[jf] = __builtin_amdgcn_mfma_f32_16x16x32_f16(fqh[ks], fkh, s1[jf], 0, 0, 0);
                s2[jf] = __builtin_amdgcn_mfma_f32_16x16x32_f16(fqh[ks], fkm, s2[jf], 0, 0, 0);
                s2[jf] = __builtin_amdgcn_mfma_f32_16x16x32_f16(fqm[ks], fkh, s2[jf], 0, 0, 0);
            }
        }
        float p[4][4];
        #pragma unroll
        for (int jf = 0; jf < 4; ++jf)
            #pragma unroll
            for (int r = 0; r < 4; ++r)
                p[jf][r] = (s1[jf][r] + s2[jf][r]*MS) * 0.125f;

        // ---- online softmax ----
        #pragma unroll
        for (int r = 0; r < 4; ++r) {
            float tm = fmaxf(fmaxf(p[0][r], p[1][r]), fmaxf(p[2][r], p[3][r]));
            #pragma unroll
            for (int off = 8; off > 0; off >>= 1) tm = fmaxf(tm, __shfl_xor(tm, off, 16));
            float mn = fmaxf(m_[r], tm);
            float f  = expf(m_[r] - mn);
            m_[r] = mn;
            l_[r] *= f;
            #pragma unroll
            for (int df = 0; df < 4; ++df) { o1[df][r] *= f; o2[df][r] *= f; }
            float ps = 0.f;
            #pragma unroll
            for (int jf = 0; jf < 4; ++jf) {
                p[jf][r] = expf(p[jf][r] - mn);
                ps += p[jf][r];
            }
            #pragma unroll
            for (int off = 8; off > 0; off >>= 1) ps += __shfl_xor(ps, off, 16);
            l_[r] += ps;
        }
        #pragma unroll
        for (int jf = 0; jf < 4; ++jf)
            #pragma unroll
            for (int r = 0; r < 4; ++r) {
                unsigned short ph, pm;
                cvt2(p[jf][r], ph, pm);
                Ph[wq*16 + g*4 + r][jf*16 + l15] = ph;
                Pm[wq*16 + g*4 + r][jf*16 + l15] = pm;
            }

        // ---- PV ----
        #pragma unroll
        for (int ks = 0; ks < 2; ++ks) {
            f16x8 fph = *(const f16x8*)&Ph[wq*16 + l15][ks*32 + g*8];
            f16x8 fpm = *(const f16x8*)&Pm[wq*16 + l15][ks*32 + g*8];
            #pragma unroll
            for (int df = 0; df < 4; ++df) {
                f16x8 fvh = *(const f16x8*)&Vth[df*16 + l15][ks*32 + g*8];
                f16x8 fvm = *(const f16x8*)&Vtm[df*16 + l15][ks*32 + g*8];
                o1[df] = __builtin_amdgcn_mfma_f32_16x16x32_f16(fph, fvh, o1[df], 0, 0, 0);
                o2[df] = __builtin_amdgcn_mfma_f32_16x16x32_f16(fph, fvm, o2[df], 0, 0, 0);
                o2[df] = __builtin_amdgcn_mfma_f32_16x16x32_f16(fpm, fvh, o2[df], 0, 0, 0);
            }
        }
    }

    #pragma unroll
    for (int r = 0; r < 4; ++r) {
        float inv = 1.f / l_[r];
        size_t row = (size_t)(b*576 + q0 + wq*16 + g*4 + r)*768 + qoff + l15;
        #pragma unroll
        for (int df = 0; df < 4; ++df)
            attn[row + df*16] = (o1[df][r] + o2[df][r]*MS) * inv;
    }
}

// ---------------- zero all 12 layers' expert counts in one launch ----------------
__global__ void zero_counts48(int* counts) { if (threadIdx.x < 48) counts[threadIdx.x] = 0; }

// ---------------- final b (h w) c -> b c h w ----------------
__global__ __launch_bounds__(256)
void out_transpose(const float* __restrict__ tok, float* __restrict__ out)
{
    int idx = blockIdx.x*256 + threadIdx.x;   // ((b*768+d)*24+hp)*24+wp
    int wp = idx % 24;
    int hp = (idx / 24) % 24;
    int d  = (idx / 576) % 768;
    int b  = idx / (576*768);
    out[idx] = tok[(size_t)(b*576 + hp*24 + wp)*768 + d];
}

extern "C" void kernel_launch(void* const* d_in, const int* in_sizes, int n_in,
                              void* d_out, int out_size, void* d_ws, size_t ws_size,
                              hipStream_t stream)
{
    const float* x       = (const float*)d_in[0];
    const float* patch_w = (const float*)d_in[1];
    const float* patch_b = (const float*)d_in[2];
    const float* pos     = (const float*)d_in[3];
    const float* ln1_g   = (const float*)d_in[4];
    const float* ln1_b   = (const float*)d_in[5];
    const float* qkv_w   = (const float*)d_in[6];
    const float* qkv_b   = (const float*)d_in[7];
    const float* out_w   = (const float*)d_in[8];
    const float* out_b   = (const float*)d_in[9];
    const float* ln2_g   = (const float*)d_in[10];
    const float* ln2_b   = (const float*)d_in[11];
    const float* gate_w  = (const float*)d_in[12];
    const float* gate_b  = (const float*)d_in[13];
    const float* w1      = (const float*)d_in[14];
    const float* b1      = (const float*)d_in[15];
    const float* w2      = (const float*)d_in[16];
    const float* b2      = (const float*)d_in[17];
    float* out = (float*)d_out;

    // workspace layout (floats): tok | h | scratch{qkv,attn} (hid & patches alias scratch)
    //                            | wgt | lists | counts[48]
    float* ws    = (float*)d_ws;
    float* tok   = ws;                       // 3,538,944
    float* h     = ws + 3538944;             // 3,538,944
    float* scr   = ws + 7077888;             // 14,155,776 (qkv 10,616,832 + attn 3,538,944)
    float* qkv   = scr;
    float* attn  = scr + 10616832;
    float* hid   = scr;                      // aliases qkv+attn (dead by FFN time)
    float* patches = scr;                    // 4608*256 (dead before layer loop)
    float* wgt   = ws + 21233664;            // 4608
    int*   lists = (int*)(ws + 21238272);    // 4*4608 (shared across layers)
    int*   counts= (int*)(ws + 21256704);    // 48 = 12 layers x 4 experts

    zero_counts48<<<1, 64, 0, stream>>>(counts);

    // patch embed = im2col + small-tile MFMA GEMM (mode 4 adds pos embed); 864 blocks
    im2col_kernel<<<4608, 256, 0, stream>>>(x, patches);
    gemm_small<true><<<dim3(12,72,1), 256, 0, stream>>>(patches, patch_w, patch_b, tok,
                                                        4608, 768, 256, 256, 768, 4,
                                                        nullptr, nullptr, pos);

    for (int l = 0; l < 12; ++l) {
        int* counts_l = counts + l*4;
        ln_kernel<<<4608, 256, 0, stream>>>(tok, h, ln1_g + l*768, ln1_b + l*768);
        gemm_wide<true><<<dim3(18,18,1), 512, 0, stream>>>(h, qkv_w + (size_t)l*1769472,
                                                           qkv_b + l*2304, qkv,
                                                           4608, 2304, 768, 768, 2304, 0,
                                                           nullptr, nullptr, nullptr);
        attn_kernel<<<dim3(9,12,8), 256, 0, stream>>>(qkv, attn);
        gemm_wide<true><<<dim3(6,18,1), 512, 0, stream>>>(attn, out_w + (size_t)l*589824,
                                                          out_b + l*768, tok,
                                                          4608, 768, 768, 768, 768, 1,
                                                          nullptr, nullptr, nullptr);
        ln2_gate_kernel<<<4608, 256, 0, stream>>>(tok, h, ln2_g + l*768, ln2_b + l*768,
                                                  gate_w + l*3072, gate_b + l*4,
                                                  wgt, lists, counts_l);
        gemm_wide<false><<<dim3(24,18,4), 512, 0, stream>>>(h, w1 + (size_t)l*9437184,
                                                            b1 + (size_t)l*4*3072, hid,
                                                            4608, 3072, 768, 768, 3072, 2,
                                                            lists, counts_l, nullptr);
        gemm_wide<false><<<dim3(6,18,4), 512, 0, stream>>>(hid, w2 + (size_t)l*9437184,
                                                           b2 + (size_t)l*4*768, tok,
                                                           4608, 768, 3072, 3072, 768, 3,
                                                           lists, counts_l, wgt);
    }
    out_transpose<<<13824, 256, 0, stream>>>(tok, out);
}

// Round 15
// 8168.295 us; speedup vs baseline: 1.1493x; 1.0185x over previous
//
#include <hip/hip_runtime.h>
#include <cmath>

#define TOK 4608      // B*N
#define DMODEL 768

typedef __attribute__((ext_vector_type(8))) _Float16 f16x8;
typedef __attribute__((ext_vector_type(4))) float f32x4;

__device__ __forceinline__ float gelu_exact(float x) {
    return 0.5f * x * (1.0f + erff(x * 0.70710678118654752440f));
}

// 2-limb fp16 decomposition, RN both limbs. x = h + m/2048 + delta, |delta| <= 2^-22 |x|.
// m pre-scaled by 2048: never subnormal (robust to MFMA input-denorm flush).
// RN (unbiased) is essential: r3's truncated variant had biased error -> gate flips.
__device__ __forceinline__ void cvt2(float x, unsigned short& h, unsigned short& m)
{
    _Float16 hf = (_Float16)x;
    float r = (x - (float)hf) * 2048.0f;        // exact residual (Sterbenz), rescaled
    _Float16 mf = (_Float16)r;
    h = __builtin_bit_cast(unsigned short, hf);
    m = __builtin_bit_cast(unsigned short, mf);
}

__device__ __forceinline__ void cvt2_pack8(const float4 a, const float4 b,
                                           uint4& H, uint4& M)
{
    unsigned short h[8], m[8];
    cvt2(a.x, h[0], m[0]); cvt2(a.y, h[1], m[1]);
    cvt2(a.z, h[2], m[2]); cvt2(a.w, h[3], m[3]);
    cvt2(b.x, h[4], m[4]); cvt2(b.y, h[5], m[5]);
    cvt2(b.z, h[6], m[6]); cvt2(b.w, h[7], m[7]);
    H = (uint4){ (unsigned)h[0] | ((unsigned)h[1] << 16), (unsigned)h[2] | ((unsigned)h[3] << 16),
                 (unsigned)h[4] | ((unsigned)h[5] << 16), (unsigned)h[6] | ((unsigned)h[7] << 16) };
    M = (uint4){ (unsigned)m[0] | ((unsigned)m[1] << 16), (unsigned)m[2] | ((unsigned)m[3] << 16),
                 (unsigned)m[4] | ((unsigned)m[5] << 16), (unsigned)m[6] | ((unsigned)m[7] << 16) };
}

// ---------------- im2col: patches[tokid][k] (coalesced both sides) ----------------
__global__ __launch_bounds__(256)
void im2col_kernel(const float* __restrict__ x, float* __restrict__ patches)
{
    int idx = blockIdx.x*256 + threadIdx.x;   // tokid*256 + k
    int k = idx & 255, tokid = idx >> 8;
    int b = tokid / 576, n = tokid % 576;
    int hp = n / 24, wp = n % 24;
    patches[idx] = x[(size_t)b*147456 + (size_t)(hp*16 + (k >> 4))*384 + wp*16 + (k & 15)];
}

// ---------------- LayerNorm over D=768, one block per token (ln1) ----------------
__global__ __launch_bounds__(256)
void ln_kernel(const float* __restrict__ in, float* __restrict__ out,
               const float* __restrict__ g, const float* __restrict__ bta)
{
    int tokid = blockIdx.x;
    const float* xr = in + (size_t)tokid*768;
    int t = threadIdx.x;
    float v0 = xr[t], v1 = xr[t+256], v2 = xr[t+512];
    float s = v0+v1+v2, q = v0*v0+v1*v1+v2*v2;
    for (int off = 32; off > 0; off >>= 1) {
        s += __shfl_down(s, off);
        q += __shfl_down(q, off);
    }
    __shared__ float ss[4], sq[4];
    int wv = t >> 6, ln = t & 63;
    if (ln == 0) { ss[wv] = s; sq[wv] = q; }
    __syncthreads();
    float ts = ss[0]+ss[1]+ss[2]+ss[3];
    float tq = sq[0]+sq[1]+sq[2]+sq[3];
    float mean = ts * (1.f/768.f);
    float var  = tq * (1.f/768.f) - mean*mean;
    float inv  = rsqrtf(var + 1e-5f);
    float* orow = out + (size_t)tokid*768;
    orow[t]     = (v0-mean)*inv*g[t]     + bta[t];
    orow[t+256] = (v1-mean)*inv*g[t+256] + bta[t+256];
    orow[t+512] = (v2-mean)*inv*g[t+512] + bta[t+512];
}

// ---------------- fused ln2 + gate: LN output + scores/argmax/expert lists --------
// Gate FMA sequence identical (k = t, t+256, t+512) to the old standalone gate
// kernel -> bit-identical scores, zero flip risk.
__global__ __launch_bounds__(256)
void ln2_gate_kernel(const float* __restrict__ in, float* __restrict__ out,
                     const float* __restrict__ g, const float* __restrict__ bta,
                     const float* __restrict__ gw, const float* __restrict__ gb,
                     float* __restrict__ wgt, int* __restrict__ lists,
                     int* __restrict__ counts)
{
    int tokid = blockIdx.x;
    const float* xr = in + (size_t)tokid*768;
    int t = threadIdx.x;
    float v0 = xr[t], v1 = xr[t+256], v2 = xr[t+512];
    float s = v0+v1+v2, q = v0*v0+v1*v1+v2*v2;
    for (int off = 32; off > 0; off >>= 1) {
        s += __shfl_down(s, off);
        q += __shfl_down(q, off);
    }
    __shared__ float ss[4], sq[4];
    __shared__ float red[4][4];
    int wv = t >> 6, ln = t & 63;
    if (ln == 0) { ss[wv] = s; sq[wv] = q; }
    __syncthreads();
    float ts = ss[0]+ss[1]+ss[2]+ss[3];
    float tq = sq[0]+sq[1]+sq[2]+sq[3];
    float mean = ts * (1.f/768.f);
    float var  = tq * (1.f/768.f) - mean*mean;
    float inv  = rsqrtf(var + 1e-5f);
    float y0 = (v0-mean)*inv*g[t]     + bta[t];
    float y1 = (v1-mean)*inv*g[t+256] + bta[t+256];
    float y2 = (v2-mean)*inv*g[t+512] + bta[t+512];
    float* orow = out + (size_t)tokid*768;
    orow[t] = y0; orow[t+256] = y1; orow[t+512] = y2;

    float p0, p1, p2, p3;
    p0 = fmaf(y0, gw[t], 0.f);        p0 = fmaf(y1, gw[t+256], p0);        p0 = fmaf(y2, gw[t+512], p0);
    p1 = fmaf(y0, gw[768+t], 0.f);    p1 = fmaf(y1, gw[768+t+256], p1);    p1 = fmaf(y2, gw[768+t+512], p1);
    p2 = fmaf(y0, gw[1536+t], 0.f);   p2 = fmaf(y1, gw[1536+t+256], p2);   p2 = fmaf(y2, gw[1536+t+512], p2);
    p3 = fmaf(y0, gw[2304+t], 0.f);   p3 = fmaf(y1, gw[2304+t+256], p3);   p3 = fmaf(y2, gw[2304+t+512], p3);
    for (int off = 32; off > 0; off >>= 1) {
        p0 += __shfl_down(p0, off);
        p1 += __shfl_down(p1, off);
        p2 += __shfl_down(p2, off);
        p3 += __shfl_down(p3, off);
    }
    if (ln == 0) { red[wv][0]=p0; red[wv][1]=p1; red[wv][2]=p2; red[wv][3]=p3; }
    __syncthreads();
    if (t == 0) {
        float sc[4];
        #pragma unroll
        for (int e = 0; e < 4; ++e)
            sc[e] = red[0][e]+red[1][e]+red[2][e]+red[3][e] + gb[e];
        int best = 0; float bv = sc[0];
        #pragma unroll
        for (int e = 1; e < 4; ++e) if (sc[e] > bv) { bv = sc[e]; best = e; }  // first-max tie-break
        wgt[tokid] = bv;
        int pos = atomicAdd(&counts[best], 1);
        lists[best*TOK + pos] = tokid;
    }
}

// ---------------- MFMA NT GEMM (big): 128x128 tile, BK=32 ----------------
// fp32 A/B in, cvt2 in staging; fp32 out. 3 MFMA terms (hh->acc1, hm+mh->acc2).
// launch_bounds(256,2): VGPR ~108, LDS 40KB -> up to 4 blocks/CU (no spill).
// SWZ: XCD-bijective block swizzle — dense grids only (r8 lesson: never on gather).
// mode 0: C=val  1: C+=val  2: C[gather]=gelu(val)  3: C[gather]+=wgt*val
// mode 4: C = val + pos[(row%576)*768+n]  (wgt doubles as pos pointer)
template<bool SWZ>
__global__ __launch_bounds__(256, 2)
void gemm_big(const float* __restrict__ A, const float* __restrict__ Bw,
              const float* __restrict__ bias, float* __restrict__ C,
              int M, int Nout, int K, int ldA, int ldC, int mode,
              const int* __restrict__ lists, const int* __restrict__ counts,
              const float* __restrict__ wgt)
{
    int Meff = M;
    const int* gather = nullptr;
    if (counts) {
        int e = blockIdx.z;
        Meff   = counts[e];
        gather = lists + e * TOK;
        Bw    += (size_t)e * Nout * K;
        bias  += (size_t)e * Nout;
    }
    int m0, n0;
    if constexpr (SWZ) {
        int gx  = gridDim.x;
        int nwg = gx * gridDim.y;       // requires nwg % 8 == 0
        int bid = blockIdx.y * gx + blockIdx.x;
        bid = (bid & 7) * (nwg >> 3) + (bid >> 3);
        m0 = (bid / gx) << 7; n0 = (bid % gx) << 7;
    } else {
        m0 = blockIdx.y << 7; n0 = blockIdx.x << 7;
    }
    if (m0 >= Meff) return;

    __shared__ unsigned short Ah[128][40];
    __shared__ unsigned short Am[128][40];
    __shared__ unsigned short Bh[128][40];
    __shared__ unsigned short Bm[128][40];

    int t = threadIdx.x;
    int srow = t >> 1;               // staging row 0..127
    int koff = (t & 1) << 4;         // k-offset 0 or 16

    int ar = m0 + srow;
    long agrow = -1;
    if (ar < Meff) agrow = gather ? gather[ar] : ar;
    const float* Asrc = (agrow >= 0) ? (A + (size_t)agrow*ldA + koff) : nullptr;
    const float* Bsrc = Bw + (size_t)(n0 + srow)*K + koff;

    int lane = t & 63;
    int wv   = t >> 6;
    int wm   = (wv >> 1) << 6;
    int wn   = (wv & 1) << 6;
    int r16  = lane & 15;
    int g    = lane >> 4;

    f32x4 acc1[4][4], acc2[4][4];
    #pragma unroll
    for (int i = 0; i < 4; ++i)
        #pragma unroll
        for (int j = 0; j < 4; ++j) {
            acc1[i][j] = (f32x4){0.f, 0.f, 0.f, 0.f};
            acc2[i][j] = (f32x4){0.f, 0.f, 0.f, 0.f};
        }

    float4 ra[4], rb[4];
    ra[0] = ra[1] = ra[2] = ra[3] = make_float4(0.f, 0.f, 0.f, 0.f);

    auto load_tile = [&](int k0) {
        if (Asrc) {
            ra[0] = *(const float4*)(Asrc + k0);
            ra[1] = *(const float4*)(Asrc + k0 + 4);
            ra[2] = *(const float4*)(Asrc + k0 + 8);
            ra[3] = *(const float4*)(Asrc + k0 + 12);
        }
        rb[0] = *(const float4*)(Bsrc + k0);
        rb[1] = *(const float4*)(Bsrc + k0 + 4);
        rb[2] = *(const float4*)(Bsrc + k0 + 8);
        rb[3] = *(const float4*)(Bsrc + k0 + 12);
    };

    load_tile(0);

    for (int k0 = 0; k0 < K; k0 += 32) {
        __syncthreads();
        {
            uint4 H, M_;
            cvt2_pack8(ra[0], ra[1], H, M_);
            *(uint4*)&Ah[srow][koff]   = H;
            *(uint4*)&Am[srow][koff]   = M_;
            cvt2_pack8(ra[2], ra[3], H, M_);
            *(uint4*)&Ah[srow][koff+8] = H;
            *(uint4*)&Am[srow][koff+8] = M_;
            cvt2_pack8(rb[0], rb[1], H, M_);
            *(uint4*)&Bh[srow][koff]   = H;
            *(uint4*)&Bm[srow][koff]   = M_;
            cvt2_pack8(rb[2], rb[3], H, M_);
            *(uint4*)&Bh[srow][koff+8] = H;
            *(uint4*)&Bm[srow][koff+8] = M_;
        }
        __syncthreads();
        if (k0 + 32 < K) load_tile(k0 + 32);   // prefetch hides under MFMA

        f16x8 fah[4], fam[4];
        #pragma unroll
        for (int i = 0; i < 4; ++i) {
            int ml = wm + i*16 + r16;
            fah[i] = *(const f16x8*)&Ah[ml][g*8];
            fam[i] = *(const f16x8*)&Am[ml][g*8];
        }
        #pragma unroll
        for (int j = 0; j < 4; ++j) {
            int nl = wn + j*16 + r16;
            f16x8 fbh = *(const f16x8*)&Bh[nl][g*8];
            f16x8 fbm = *(const f16x8*)&Bm[nl][g*8];
            #pragma unroll
            for (int i = 0; i < 4; ++i) {
                acc1[i][j] = __builtin_amdgcn_mfma_f32_16x16x32_f16(fah[i], fbh, acc1[i][j], 0, 0, 0);
                acc2[i][j] = __builtin_amdgcn_mfma_f32_16x16x32_f16(fah[i], fbm, acc2[i][j], 0, 0, 0);
                acc2[i][j] = __builtin_amdgcn_mfma_f32_16x16x32_f16(fam[i], fbh, acc2[i][j], 0, 0, 0);
            }
        }
    }

    const float MS = 1.0f / 2048.0f;
    float biasv[4];
    #pragma unroll
    for (int j = 0; j < 4; ++j) biasv[j] = bias[n0 + wn + j*16 + r16];

    #pragma unroll
    for (int i = 0; i < 4; ++i) {
        int mb = m0 + wm + i*16 + (g << 2);
        #pragma unroll
        for (int r = 0; r < 4; ++r) {
            int m = mb + r;
            if (m >= Meff) continue;
            int row = gather ? gather[m] : m;
            size_t rowoff = (size_t)row*ldC + n0 + wn + r16;
            float w = (mode == 3) ? wgt[row] : 0.f;
            #pragma unroll
            for (int j = 0; j < 4; ++j) {
                float val = acc1[i][j][r] + acc2[i][j][r] * MS + biasv[j];
                size_t off = rowoff + j*16;
                if      (mode == 0) C[off] = val;
                else if (mode == 1) C[off] += val;
                else if (mode == 2) C[off] = gelu_exact(val);
                else if (mode == 3) C[off] += w * val;
                else C[off] = val + wgt[(size_t)(row % 576)*768 + n0 + wn + j*16 + r16];
            }
        }
    }
}

// ---------------- MFMA NT GEMM (small): 64x64 tile, BK=64 ----------------
// For grids that would otherwise have fewer blocks than CUs (out-proj, w2, patch).
// threads 0..127 stage A rows, 128..255 stage B rows (32 floats each).
template<bool SWZ>
__global__ __launch_bounds__(256, 2)
void gemm_small(const float* __restrict__ A, const float* __restrict__ Bw,
                const float* __restrict__ bias, float* __restrict__ C,
                int M, int Nout, int K, int ldA, int ldC, int mode,
                const int* __restrict__ lists, const int* __restrict__ counts,
                const float* __restrict__ wgt)
{
    int Meff = M;
    const int* gather = nullptr;
    if (counts) {
        int e = blockIdx.z;
        Meff   = counts[e];
        gather = lists + e * TOK;
        Bw    += (size_t)e * Nout * K;
        bias  += (size_t)e * Nout;
    }
    int m0, n0;
    if constexpr (SWZ) {
        int gx  = gridDim.x;
        int nwg = gx * gridDim.y;       // requires nwg % 8 == 0
        int bid = blockIdx.y * gx + blockIdx.x;
        bid = (bid & 7) * (nwg >> 3) + (bid >> 3);
        m0 = (bid / gx) << 6; n0 = (bid % gx) << 6;
    } else {
        m0 = blockIdx.y << 6; n0 = blockIdx.x << 6;
    }
    if (m0 >= Meff) return;

    __shared__ unsigned short Ah[64][72];
    __shared__ unsigned short Am[64][72];
    __shared__ unsigned short Bh[64][72];
    __shared__ unsigned short Bm[64][72];

    int t = threadIdx.x;
    int srow  = t >> 1;              // 0..127: <64 => A row, else B row
    int khalf = (t & 1) << 5;        // 0 or 32
    bool isA = srow < 64;
    int row  = isA ? srow : (srow - 64);

    const float* src = nullptr;
    if (isA) {
        int ar = m0 + row;
        if (ar < Meff) {
            long agrow = gather ? gather[ar] : ar;
            src = A + (size_t)agrow*ldA + khalf;
        }
    } else {
        src = Bw + (size_t)(n0 + row)*K + khalf;
    }

    int lane = t & 63;
    int wv   = t >> 6;
    int wm   = (wv >> 1) << 5;       // 0 / 32
    int wn   = (wv & 1) << 5;        // 0 / 32
    int r16  = lane & 15;
    int g    = lane >> 4;

    f32x4 acc1[2][2], acc2[2][2];
    #pragma unroll
    for (int i = 0; i < 2; ++i)
        #pragma unroll
        for (int j = 0; j < 2; ++j) {
            acc1[i][j] = (f32x4){0.f, 0.f, 0.f, 0.f};
            acc2[i][j] = (f32x4){0.f, 0.f, 0.f, 0.f};
        }

    float4 rr[8];
    #pragma unroll
    for (int i = 0; i < 8; ++i) rr[i] = make_float4(0.f, 0.f, 0.f, 0.f);

    auto load_tile = [&](int k0) {
        if (src) {
            #pragma unroll
            for (int i = 0; i < 8; ++i) rr[i] = *(const float4*)(src + k0 + 4*i);
        }
    };

    load_tile(0);

    for (int k0 = 0; k0 < K; k0 += 64) {
        __syncthreads();
        {
            unsigned short (*Xh)[72] = isA ? Ah : Bh;
            unsigned short (*Xm)[72] = isA ? Am : Bm;
            #pragma unroll
            for (int i = 0; i < 8; i += 2) {
                uint4 H, M_;
                cvt2_pack8(rr[i], rr[i+1], H, M_);
                *(uint4*)&Xh[row][khalf + 4*i] = H;
                *(uint4*)&Xm[row][khalf + 4*i] = M_;
            }
        }
        __syncthreads();
        if (k0 + 64 < K) load_tile(k0 + 64);   // prefetch hides under MFMA

        #pragma unroll
        for (int ks = 0; ks < 2; ++ks) {
            f16x8 fah[2], fam[2];
            #pragma unroll
            for (int i = 0; i < 2; ++i) {
                int ml = wm + i*16 + r16;
                fah[i] = *(const f16x8*)&Ah[ml][ks*32 + g*8];
                fam[i] = *(const f16x8*)&Am[ml][ks*32 + g*8];
            }
            #pragma unroll
            for (int j = 0; j < 2; ++j) {
                int nl = wn + j*16 + r16;
                f16x8 fbh = *(const f16x8*)&Bh[nl][ks*32 + g*8];
                f16x8 fbm = *(const f16x8*)&Bm[nl][ks*32 + g*8];
                #pragma unroll
                for (int i = 0; i < 2; ++i) {
                    acc1[i][j] = __builtin_amdgcn_mfma_f32_16x16x32_f16(fah[i], fbh, acc1[i][j], 0, 0, 0);
                    acc2[i][j] = __builtin_amdgcn_mfma_f32_16x16x32_f16(fah[i], fbm, acc2[i][j], 0, 0, 0);
                    acc2[i][j] = __builtin_amdgcn_mfma_f32_16x16x32_f16(fam[i], fbh, acc2[i][j], 0, 0, 0);
                }
            }
        }
    }

    const float MS = 1.0f / 2048.0f;
    float biasv[2];
    #pragma unroll
    for (int j = 0; j < 2; ++j) biasv[j] = bias[n0 + wn + j*16 + r16];

    #pragma unroll
    for (int i = 0; i < 2; ++i) {
        int mb = m0 + wm + i*16 + (g << 2);
        #pragma unroll
        for (int r = 0; r < 4; ++r) {
            int m = mb + r;
            if (m >= Meff) continue;
            int rowc = gather ? gather[m] : m;
            size_t rowoff = (size_t)rowc*ldC + n0 + wn + r16;
            float w = (mode == 3) ? wgt[rowc] : 0.f;
            #pragma unroll
            for (int j = 0; j < 2; ++j) {
                float val = acc1[i][j][r] + acc2[i][j][r] * MS + biasv[j];
                size_t off = rowoff + j*16;
                if      (mode == 0) C[off] = val;
                else if (mode == 1) C[off] += val;
                else if (mode == 2) C[off] = gelu_exact(val);
                else if (mode == 3) C[off] += w * val;
                else C[off] = val + wgt[(size_t)(rowc % 576)*768 + n0 + wn + j*16 + r16];
            }
        }
    }
}

// ---------------- attention (MFMA flash): one block = 64 q-rows x (head, batch) ----
__global__ __launch_bounds__(256)
void attn_kernel(const float* __restrict__ qkv, float* __restrict__ attn)
{
    int q0 = blockIdx.x << 6;
    int h  = blockIdx.y;
    int b  = blockIdx.z;
    const float* base = qkv + (size_t)b * 576 * 2304;
    int qoff = h << 6, koff = 768 + (h << 6), voff = 1536 + (h << 6);

    __shared__ unsigned short Qh[64][72], Qm[64][72];
    __shared__ unsigned short Kh[64][72], Km[64][72];
    __shared__ unsigned short Vth[64][72], Vtm[64][72];   // transposed: [d][j]
    __shared__ unsigned short Ph[64][72], Pm[64][72];

    int t    = threadIdx.x;
    int lane = t & 63;
    int wq   = t >> 6;
    int l15  = lane & 15;
    int g    = lane >> 4;

    int srow = t >> 2;           // staging row 0..63
    int sq   = t & 3;            // quarter

    // ---- stage Q ----
    {
        const float* src = &base[(size_t)(q0 + srow)*2304 + qoff + (sq << 4)];
        #pragma unroll
        for (int k = 0; k < 16; k += 4) {
            float4 v = *(const float4*)(src + k);
            ushort4 hh, mm;
            cvt2(v.x, hh.x, mm.x); cvt2(v.y, hh.y, mm.y);
            cvt2(v.z, hh.z, mm.z); cvt2(v.w, hh.w, mm.w);
            *(ushort4*)&Qh[srow][(sq << 4) + k] = hh;
            *(ushort4*)&Qm[srow][(sq << 4) + k] = mm;
        }
    }
    __syncthreads();

    f16x8 fqh[2], fqm[2];
    #pragma unroll
    for (int ks = 0; ks < 2; ++ks) {
        fqh[ks] = *(const f16x8*)&Qh[wq*16 + l15][ks*32 + g*8];
        fqm[ks] = *(const f16x8*)&Qm[wq*16 + l15][ks*32 + g*8];
    }

    float4 rk[4], rv[4];
    {
        const float* ks_ = &base[(size_t)srow*2304 + koff + (sq << 4)];
        const float* vs_ = &base[(size_t)srow*2304 + voff + (sq << 2)];
        #pragma unroll
        for (int k = 0; k < 4; ++k) rk[k] = *(const float4*)(ks_ + 4*k);
        #pragma unroll
        for (int k = 0; k < 4; ++k) rv[k] = *(const float4*)(vs_ + 16*k);
    }

    f32x4 o1[4], o2[4];
    #pragma unroll
    for (int df = 0; df < 4; ++df) {
        o1[df] = (f32x4){0.f,0.f,0.f,0.f};
        o2[df] = (f32x4){0.f,0.f,0.f,0.f};
    }
    float m_[4] = {-3.4e38f,-3.4e38f,-3.4e38f,-3.4e38f};
    float l_[4] = {0.f,0.f,0.f,0.f};
    const float MS = 1.0f / 2048.0f;

    for (int j0 = 0; j0 < 576; j0 += 64) {
        __syncthreads();   // previous tile's LDS reads done
        #pragma unroll
        for (int k = 0; k < 4; ++k) {
            ushort4 hh, mm;
            cvt2(rk[k].x, hh.x, mm.x); cvt2(rk[k].y, hh.y, mm.y);
            cvt2(rk[k].z, hh.z, mm.z); cvt2(rk[k].w, hh.w, mm.w);
            *(ushort4*)&Kh[srow][(sq << 4) + 4*k] = hh;
            *(ushort4*)&Km[srow][(sq << 4) + 4*k] = mm;
        }
        #pragma unroll
        for (int k = 0; k < 4; ++k) {
            ushort4 hh, mm;
            cvt2(rv[k].x, hh.x, mm.x); cvt2(rv[k].y, hh.y, mm.y);
            cvt2(rv[k].z, hh.z, mm.z); cvt2(rv[k].w, hh.w, mm.w);
            int dbase = (sq << 2) + (k << 4);
            Vth[dbase+0][srow] = hh.x; Vtm[dbase+0][srow] = mm.x;
            Vth[dbase+1][srow] = hh.y; Vtm[dbase+1][srow] = mm.y;
            Vth[dbase+2][srow] = hh.z; Vtm[dbase+2][srow] = mm.z;
            Vth[dbase+3][srow] = hh.w; Vtm[dbase+3][srow] = mm.w;
        }
        __syncthreads();
        int jn = j0 + 64;
        if (jn < 576) {
            const float* ks_ = &base[(size_t)(jn + srow)*2304 + koff + (sq << 4)];
            const float* vs_ = &base[(size_t)(jn + srow)*2304 + voff + (sq << 2)];
            #pragma unroll
            for (int k = 0; k < 4; ++k) rk[k] = *(const float4*)(ks_ + 4*k);
            #pragma unroll
            for (int k = 0; k < 4; ++k) rv[k] = *(const float4*)(vs_ + 16*k);
        }

        // ---- QK^T ----
        f32x4 s1[4], s2[4];
        #pragma unroll
        for (int jf = 0; jf < 4; ++jf) {
            s1[jf] = (f32x4){0.f,0.f,0.f,0.f};
            s2[jf] = (f32x4){0.f,0.f,0.f,0.f};
        }
        #pragma unroll
        for (int jf = 0; jf < 4; ++jf) {
            #pragma unroll
            for (int ks = 0; ks < 2; ++ks) {
                f16x8 fkh = *(const f16x8*)&Kh[jf*16 + l15][ks*32 + g*8];
                f16x8 fkm = *(const f16x8*)&Km[jf*16 + l15][ks*32 + g*8];
                s1[jf] = __builtin_amdgcn_mfma_f32_16x16x32_f16(fqh[ks], fkh, s1[jf], 0, 0, 0);
                s2[jf] = __builtin_amdgcn_mfma_f32_16x16x32_f16(fqh[ks], fkm, s2[jf], 0, 0, 0);
                s2[jf] = __builtin_amdgcn_mfma_f32_16x16x32_f16(fqm[ks], fkh, s2[jf], 0, 0, 0);
            }
        }
        float p[4][4];
        #pragma unroll
        for (int jf = 0; jf < 4; ++jf)
            #pragma unroll
            for (int r = 0; r < 4; ++r)
                p[jf][r] = (s1[jf][r] + s2[jf][r]*MS) * 0.125f;

        // ---- online softmax ----
        #pragma unroll
        for (int r = 0; r < 4; ++r) {
            float tm = fmaxf(fmaxf(p[0][r], p[1][r]), fmaxf(p[2][r], p[3][r]));
            #pragma unroll
            for (int off = 8; off > 0; off >>= 1) tm = fmaxf(tm, __shfl_xor(tm, off, 16));
            float mn = fmaxf(m_[r], tm);
            float f  = expf(m_[r] - mn);
            m_[r] = mn;
            l_[r] *= f;
            #pragma unroll
            for (int df = 0; df < 4; ++df) { o1[df][r] *= f; o2[df][r] *= f; }
            float ps = 0.f;
            #pragma unroll
            for (int jf = 0; jf < 4; ++jf) {
                p[jf][r] = expf(p[jf][r] - mn);
                ps += p[jf][r];
            }
            #pragma unroll
            for (int off = 8; off > 0; off >>= 1) ps += __shfl_xor(ps, off, 16);
            l_[r] += ps;
        }
        #pragma unroll
        for (int jf = 0; jf < 4; ++jf)
            #pragma unroll
            for (int r = 0; r < 4; ++r) {
                unsigned short ph, pm;
                cvt2(p[jf][r], ph, pm);
                Ph[wq*16 + g*4 + r][jf*16 + l15] = ph;
                Pm[wq*16 + g*4 + r][jf*16 + l15] = pm;
            }

        // ---- PV ----
        #pragma unroll
        for (int ks = 0; ks < 2; ++ks) {
            f16x8 fph = *(const f16x8*)&Ph[wq*16 + l15][ks*32 + g*8];
            f16x8 fpm = *(const f16x8*)&Pm[wq*16 + l15][ks*32 + g*8];
            #pragma unroll
            for (int df = 0; df < 4; ++df) {
                f16x8 fvh = *(const f16x8*)&Vth[df*16 + l15][ks*32 + g*8];
                f16x8 fvm = *(const f16x8*)&Vtm[df*16 + l15][ks*32 + g*8];
                o1[df] = __builtin_amdgcn_mfma_f32_16x16x32_f16(fph, fvh, o1[df], 0, 0, 0);
                o2[df] = __builtin_amdgcn_mfma_f32_16x16x32_f16(fph, fvm, o2[df], 0, 0, 0);
                o2[df] = __builtin_amdgcn_mfma_f32_16x16x32_f16(fpm, fvh, o2[df], 0, 0, 0);
            }
        }
    }

    #pragma unroll
    for (int r = 0; r < 4; ++r) {
        float inv = 1.f / l_[r];
        size_t row = (size_t)(b*576 + q0 + wq*16 + g*4 + r)*768 + qoff + l15;
        #pragma unroll
        for (int df = 0; df < 4; ++df)
            attn[row + df*16] = (o1[df][r] + o2[df][r]*MS) * inv;
    }
}

// ---------------- zero all 12 layers' expert counts in one launch ----------------
__global__ void zero_counts48(int* counts) { if (threadIdx.x < 48) counts[threadIdx.x] = 0; }

// ---------------- final b (h w) c -> b c h w ----------------
__global__ __launch_bounds__(256)
void out_transpose(const float* __restrict__ tok, float* __restrict__ out)
{
    int idx = blockIdx.x*256 + threadIdx.x;   // ((b*768+d)*24+hp)*24+wp
    int wp = idx % 24;
    int hp = (idx / 24) % 24;
    int d  = (idx / 576) % 768;
    int b  = idx / (576*768);
    out[idx] = tok[(size_t)(b*576 + hp*24 + wp)*768 + d];
}

extern "C" void kernel_launch(void* const* d_in, const int* in_sizes, int n_in,
                              void* d_out, int out_size, void* d_ws, size_t ws_size,
                              hipStream_t stream)
{
    const float* x       = (const float*)d_in[0];
    const float* patch_w = (const float*)d_in[1];
    const float* patch_b = (const float*)d_in[2];
    const float* pos     = (const float*)d_in[3];
    const float* ln1_g   = (const float*)d_in[4];
    const float* ln1_b   = (const float*)d_in[5];
    const float* qkv_w   = (const float*)d_in[6];
    const float* qkv_b   = (const float*)d_in[7];
    const float* out_w   = (const float*)d_in[8];
    const float* out_b   = (const float*)d_in[9];
    const float* ln2_g   = (const float*)d_in[10];
    const float* ln2_b   = (const float*)d_in[11];
    const float* gate_w  = (const float*)d_in[12];
    const float* gate_b  = (const float*)d_in[13];
    const float* w1      = (const float*)d_in[14];
    const float* b1      = (const float*)d_in[15];
    const float* w2      = (const float*)d_in[16];
    const float* b2      = (const float*)d_in[17];
    float* out = (float*)d_out;

    // workspace layout (floats): tok | h | scratch{qkv,attn} (hid & patches alias scratch)
    //                            | wgt | lists | counts[48]
    float* ws    = (float*)d_ws;
    float* tok   = ws;                       // 3,538,944
    float* h     = ws + 3538944;             // 3,538,944
    float* scr   = ws + 7077888;             // 14,155,776 (qkv 10,616,832 + attn 3,538,944)
    float* qkv   = scr;
    float* attn  = scr + 10616832;
    float* hid   = scr;                      // aliases qkv+attn (dead by FFN time)
    float* patches = scr;                    // 4608*256 (dead before layer loop)
    float* wgt   = ws + 21233664;            // 4608
    int*   lists = (int*)(ws + 21238272);    // 4*4608 (shared across layers)
    int*   counts= (int*)(ws + 21256704);    // 48 = 12 layers x 4 experts

    zero_counts48<<<1, 64, 0, stream>>>(counts);

    // patch embed = im2col + small-tile MFMA GEMM (mode 4 adds pos embed); 864 blocks
    im2col_kernel<<<4608, 256, 0, stream>>>(x, patches);
    gemm_small<true><<<dim3(12,72,1), 256, 0, stream>>>(patches, patch_w, patch_b, tok,
                                                        4608, 768, 256, 256, 768, 4,
                                                        nullptr, nullptr, pos);

    for (int l = 0; l < 12; ++l) {
        int* counts_l = counts + l*4;
        ln_kernel<<<4608, 256, 0, stream>>>(tok, h, ln1_g + l*768, ln1_b + l*768);
        gemm_big<true><<<dim3(18,36,1), 256, 0, stream>>>(h, qkv_w + (size_t)l*1769472,
                                                          qkv_b + l*2304, qkv,
                                                          4608, 2304, 768, 768, 2304, 0,
                                                          nullptr, nullptr, nullptr);
        attn_kernel<<<dim3(9,12,8), 256, 0, stream>>>(qkv, attn);
        gemm_small<true><<<dim3(12,72,1), 256, 0, stream>>>(attn, out_w + (size_t)l*589824,
                                                            out_b + l*768, tok,
                                                            4608, 768, 768, 768, 768, 1,
                                                            nullptr, nullptr, nullptr);
        ln2_gate_kernel<<<4608, 256, 0, stream>>>(tok, h, ln2_g + l*768, ln2_b + l*768,
                                                  gate_w + l*3072, gate_b + l*4,
                                                  wgt, lists, counts_l);
        gemm_big<false><<<dim3(24,36,4), 256, 0, stream>>>(h, w1 + (size_t)l*9437184,
                                                           b1 + (size_t)l*4*3072, hid,
                                                           4608, 3072, 768, 768, 3072, 2,
                                                           lists, counts_l, nullptr);
        gemm_small<false><<<dim3(12,72,4), 256, 0, stream>>>(hid, w2 + (size_t)l*9437184,
                                                             b2 + (size_t)l*4*768, tok,
                                                             4608, 768, 3072, 3072, 768, 3,
                                                             lists, counts_l, wgt);
    }
    out_transpose<<<13824, 256, 0, stream>>>(tok, out);
}